// Round 11
// baseline (903.023 us; speedup 1.0000x reference)
//
#include <hip/hip_runtime.h>

// ---- problem constants ----
#define B_     4
#define N_     8192
#define MD_    512
#define OC_    536        // HEADS*(FEAT+3)
#define HEADS_ 8
#define FEAT_  64
#define NC_    32768      // 32^3 cells
#define ZTOT_  67108864ll // B*HEADS*FEAT*NC
#define NPTS_  262144     // B*HEADS*N
#define NPSE_  16384      // pseudo-entries per bh (2 per point)
#define NWIN_  256        // 128-cell windows per bh
#define NKEYS_ 786432.0f  // B*HEADS*3*N

typedef __bf16 bf16x8 __attribute__((ext_vector_type(8)));
typedef float  f32x4  __attribute__((ext_vector_type(4)));

__device__ __forceinline__ unsigned short f2bf(float f) {
  unsigned int u = __float_as_uint(f);
  u = (u + 0x7FFFu + ((u >> 16) & 1u)) >> 16;   // round-to-nearest-even
  return (unsigned short)u;
}

// ============================================================
// convW: W rows 24..535 -> bf16 [512][512]
// ============================================================
__global__ __launch_bounds__(256) void convw_kernel(const float* __restrict__ W,
                                                    unsigned short* __restrict__ Wbf) {
  int i = (blockIdx.x * 256 + threadIdx.x) * 4;
  float4 v = *(const float4*)&W[24 * 512 + i];
  ushort4 o;
  o.x = f2bf(v.x); o.y = f2bf(v.y); o.z = f2bf(v.z); o.w = f2bf(v.w);
  *(ushort4*)&Wbf[i] = o;
}

// ============================================================
// convXt: X[b][k][n] f32 -> Xt[b][n][k] bf16 (transposed)
// ============================================================
__global__ __launch_bounds__(256) void convxt_kernel(const float* __restrict__ X,
                                                     unsigned short* __restrict__ Xt) {
  const int n0 = blockIdx.x * 64;
  const int k0 = blockIdx.y * 64;
  const int b  = blockIdx.z;
  __shared__ float T[64][65];
  const int t = threadIdx.x;
#pragma unroll
  for (int i = 0; i < 16; ++i) {
    int idx = t + i * 256;
    int kk = idx >> 6, nn = idx & 63;
    T[kk][nn] = X[((size_t)b * MD_ + k0 + kk) * N_ + n0 + nn];
  }
  __syncthreads();
  const int sub = t & 7;
  const int nb  = t >> 3;
#pragma unroll
  for (int i = 0; i < 2; ++i) {
    int nn = nb + i * 32;
    ushort4 o0, o1;
    o0.x = f2bf(T[sub * 8 + 0][nn]); o0.y = f2bf(T[sub * 8 + 1][nn]);
    o0.z = f2bf(T[sub * 8 + 2][nn]); o0.w = f2bf(T[sub * 8 + 3][nn]);
    o1.x = f2bf(T[sub * 8 + 4][nn]); o1.y = f2bf(T[sub * 8 + 5][nn]);
    o1.z = f2bf(T[sub * 8 + 6][nn]); o1.w = f2bf(T[sub * 8 + 7][nn]);
    unsigned short* dst = Xt + ((size_t)b * N_ + n0 + nn) * MD_ + k0 + sub * 8;
    *(ushort4*)dst = o0;
    *(ushort4*)(dst + 4) = o1;
  }
}

// ============================================================
// gemm_keys: fp32-exact GEMM for key channels (rows 0..23)
// writes kvk[b][24][N] + fused per-channel stats
// ============================================================
__global__ __launch_bounds__(256) void gemm_keys(const float* __restrict__ W,
                                                 const float* __restrict__ X,
                                                 float* __restrict__ kvk,
                                                 float* __restrict__ ssum,
                                                 float* __restrict__ s2sum) {
  const int n0 = blockIdx.x * 256;
  const int b  = blockIdx.y;
  __shared__ float Wt[32][26];
  __shared__ float In[32][260];
  const int t  = threadIdx.x;
  const int cg = t & 63;
  const int rb = (t >> 6) * 6;
  float acc[6][4];
#pragma unroll
  for (int r = 0; r < 6; ++r)
#pragma unroll
    for (int c = 0; c < 4; ++c) acc[r][c] = 0.f;
  const float* Xb = X + (size_t)b * MD_ * N_;
  for (int k0 = 0; k0 < MD_; k0 += 32) {
#pragma unroll
    for (int i = 0; i < 3; ++i) {
      int idx = t * 3 + i;
      int m = idx % 24, k = idx / 24;
      Wt[k][m] = W[(size_t)m * MD_ + k0 + k];
    }
#pragma unroll
    for (int i = 0; i < 8; ++i) {
      int slot = t + i * 256;
      int k = slot >> 6, n4 = slot & 63;
      float4 v = *(const float4*)(Xb + (size_t)(k0 + k) * N_ + n0 + n4 * 4);
      *(float4*)&In[k][n4 * 4] = v;
    }
    __syncthreads();
#pragma unroll
    for (int k = 0; k < 32; ++k) {
      float4 bv = *(const float4*)&In[k][cg * 4];
#pragma unroll
      for (int r = 0; r < 6; ++r) {
        float a = Wt[k][rb + r];
        acc[r][0] = fmaf(a, bv.x, acc[r][0]);
        acc[r][1] = fmaf(a, bv.y, acc[r][1]);
        acc[r][2] = fmaf(a, bv.z, acc[r][2]);
        acc[r][3] = fmaf(a, bv.w, acc[r][3]);
      }
    }
    __syncthreads();
  }
#pragma unroll
  for (int r = 0; r < 6; ++r) {
    float* dst = kvk + ((size_t)b * 24 + rb + r) * N_ + n0 + cg * 4;
    *(float4*)dst = *(float4*)&acc[r][0];
    float s = acc[r][0] + acc[r][1] + acc[r][2] + acc[r][3];
    float s2 = acc[r][0]*acc[r][0] + acc[r][1]*acc[r][1] +
               acc[r][2]*acc[r][2] + acc[r][3]*acc[r][3];
#pragma unroll
    for (int off = 32; off; off >>= 1) {
      s  += __shfl_down(s, off);
      s2 += __shfl_down(s2, off);
    }
    if (cg == 0) { atomicAdd(&ssum[rb + r], s); atomicAdd(&s2sum[rb + r], s2); }
  }
}

// ============================================================
// gemm_mfma: bf16 MFMA GEMM for value channels; writes directly
// to vals[bh][n][f] (un-BN'd) + fused per-channel stats.
// ============================================================
__global__ __launch_bounds__(256) void gemm_mfma(const unsigned short* __restrict__ Wbf,
                                                 const unsigned short* __restrict__ Xt,
                                                 float* __restrict__ vals,
                                                 float* __restrict__ ssum,
                                                 float* __restrict__ s2sum) {
  const int m0 = blockIdx.x * 128;
  const int n0 = blockIdx.y * 128;
  const int b  = blockIdx.z;
  __shared__ __align__(16) unsigned short Al[128][72];
  __shared__ __align__(16) unsigned short Bl[128][72];
  const int t = threadIdx.x;
  const int lane = t & 63, wave = t >> 6;
  const int wm = wave >> 1, wn = wave & 1;
  f32x4 acc[4][4];
#pragma unroll
  for (int mi = 0; mi < 4; ++mi)
#pragma unroll
    for (int ni = 0; ni < 4; ++ni)
#pragma unroll
      for (int j = 0; j < 4; ++j) acc[mi][ni][j] = 0.f;

  const unsigned short* Xb = Xt + ((size_t)b * N_ + n0) * MD_;
  for (int k0 = 0; k0 < MD_; k0 += 64) {
#pragma unroll
    for (int i = 0; i < 4; ++i) {
      int chunk = t + i * 256;
      int r = chunk >> 3, c = chunk & 7;
      *(uint4*)&Al[r][c * 8] =
          *(const uint4*)&Wbf[(size_t)(m0 + r) * MD_ + k0 + c * 8];
    }
#pragma unroll
    for (int i = 0; i < 4; ++i) {
      int chunk = t + i * 256;
      int r = chunk >> 3, c = chunk & 7;
      *(uint4*)&Bl[r][c * 8] =
          *(const uint4*)&Xb[(size_t)r * MD_ + k0 + c * 8];
    }
    __syncthreads();
#pragma unroll
    for (int ks = 0; ks < 2; ++ks) {
      bf16x8 af[4], bfr[4];
#pragma unroll
      for (int mi = 0; mi < 4; ++mi)
        af[mi] = *(const bf16x8*)&Al[wm * 64 + mi * 16 + (lane & 15)]
                                    [ks * 32 + (lane >> 4) * 8];
#pragma unroll
      for (int ni = 0; ni < 4; ++ni)
        bfr[ni] = *(const bf16x8*)&Bl[wn * 64 + ni * 16 + (lane & 15)]
                                     [ks * 32 + (lane >> 4) * 8];
#pragma unroll
      for (int mi = 0; mi < 4; ++mi)
#pragma unroll
        for (int ni = 0; ni < 4; ++ni)
          acc[mi][ni] = __builtin_amdgcn_mfma_f32_16x16x32_bf16(
              af[mi], bfr[ni], acc[mi][ni], 0, 0, 0);
    }
    __syncthreads();
  }
#pragma unroll
  for (int mi = 0; mi < 4; ++mi)
#pragma unroll
    for (int j = 0; j < 4; ++j) {
      float s  = acc[mi][0][j] + acc[mi][1][j] + acc[mi][2][j] + acc[mi][3][j];
      float s2 = acc[mi][0][j]*acc[mi][0][j] + acc[mi][1][j]*acc[mi][1][j] +
                 acc[mi][2][j]*acc[mi][2][j] + acc[mi][3][j]*acc[mi][3][j];
#pragma unroll
      for (int off = 1; off < 16; off <<= 1) {
        s  += __shfl_xor(s, off);
        s2 += __shfl_xor(s2, off);
      }
      if ((lane & 15) == 0) {
        int mg = m0 + wm * 64 + mi * 16 + (lane >> 4) * 4 + j;
        atomicAdd(&ssum[24 + mg], s);
        atomicAdd(&s2sum[24 + mg], s2);
      }
    }
#pragma unroll
  for (int mi = 0; mi < 4; ++mi) {
#pragma unroll
    for (int ni = 0; ni < 4; ++ni) {
      int mg = m0 + wm * 64 + mi * 16 + (lane >> 4) * 4;
      int h = mg >> 6, f = mg & 63;
      int n = n0 + wn * 64 + ni * 16 + (lane & 15);
      float* dst = vals + (((size_t)(b * 8 + h) * N_ + n) << 6) + f;
#pragma unroll
      for (int j = 0; j < 4; ++j) dst[j] = acc[mi][ni][j];
    }
  }
}

// ============================================================
// bnfin: finalize BN -> scale/shift per channel
// ============================================================
__global__ __launch_bounds__(256) void bnfin_kernel(const float* __restrict__ ssum,
                                                    const float* __restrict__ s2sum,
                                                    const float* __restrict__ kg,
                                                    const float* __restrict__ kb,
                                                    const float* __restrict__ vg,
                                                    const float* __restrict__ vb,
                                                    float* __restrict__ scale,
                                                    float* __restrict__ shift) {
  const int o = blockIdx.x * 256 + threadIdx.x;
  if (o >= OC_) return;
  const float inv = 1.0f / (B_ * N_);
  float mu  = ssum[o] * inv;
  float var = s2sum[o] * inv - mu * mu;
  float g, be;
  if (o < 24) { g = kg[o]; be = kb[o]; }
  else        { g = vg[o - 24]; be = vb[o - 24]; }
  float sc = g * rsqrtf(var + 1e-5f);
  scale[o] = sc;
  shift[o] = be - mu * sc;
}

// ============================================================
// passk: per-point keys -> {r0,r1,r2, cell} + keys mean/var
// ============================================================
__global__ __launch_bounds__(256) void passk_kernel(const float* __restrict__ kvk,
                                                    const float* __restrict__ orig,
                                                    const float* __restrict__ proj,
                                                    const float* __restrict__ scale,
                                                    const float* __restrict__ shift,
                                                    float4* __restrict__ cellr,
                                                    float* __restrict__ kacc) {
  const int p = blockIdx.x * 256 + threadIdx.x;
  const int bh = p >> 13, n = p & (N_ - 1);
  const int b = bh >> 3, h = bh & 7;
  const float* Kb = kvk + (size_t)b * 24 * N_;
  float pt[3];
#pragma unroll
  for (int k = 0; k < 3; ++k) {
    int ch = h * 3 + k;
    float kr = fmaf(Kb[(size_t)ch * N_ + n], scale[ch], shift[ch]);
    pt[k] = orig[((size_t)b * 3 + k) * N_ + n] + kr;
  }
  float ksum = 0.f, ksq = 0.f;
  int cell = 0;
  float rr[3];
#pragma unroll
  for (int d = 0; d < 3; ++d) {
    const float* pr = proj + (h * 3 + d) * 3;
    float key = pr[0] * pt[0] + pr[1] * pt[1] + pr[2] * pt[2];
    ksum += key; ksq += key * key;
    float lat = tanhf(key);
    float c = (lat + 1.0f) * 15.5f;
    float fl = floorf(c);
    fl = fminf(fmaxf(fl, 0.0f), 30.0f);
    rr[d] = c - fl;
    cell += (int)fl * ((d == 0) ? 1024 : (d == 1) ? 32 : 1);
  }
  cellr[p] = make_float4(rr[0], rr[1], rr[2], __int_as_float(cell));
#pragma unroll
  for (int off = 32; off; off >>= 1) {
    ksum += __shfl_down(ksum, off);
    ksq  += __shfl_down(ksq, off);
  }
  if ((threadIdx.x & 63) == 0) {
    atomicAdd(&kacc[0], ksum);
    atomicAdd(&kacc[1], ksq);
  }
}

// ============================================================
// sortk: per-bh counting sort of 16384 PSEUDO-entries (2/point:
// base cell with half=0, cell+1024 with half=1). Two scatter
// phases (half0 then half1, barrier between) so same-cell runs
// never interleave halves. Saves 128-cell window boundaries:
// wlo[w]=pref[max(0,wb-33)], whi[w]=pref[min(NC,wb+128)].
// Entry: {r0,r1,r2, bitcast(cell | n<<15 | half<<28)}
// ============================================================
__global__ __launch_bounds__(1024, 1) void sortk_kernel(const float4* __restrict__ cellr,
                                                        float4* __restrict__ sorted,
                                                        int* __restrict__ wlo,
                                                        int* __restrict__ whi) {
  const int bh = blockIdx.x;
  __shared__ int hist[NC_];      // 128 KiB
  __shared__ int wsum[16];
  const int t = threadIdx.x;
  for (int i = t; i < NC_; i += 1024) hist[i] = 0;
  __syncthreads();
  const float4* cr = cellr + (size_t)bh * N_;
  float4 mreg[8];
#pragma unroll
  for (int i = 0; i < 8; ++i) {
    mreg[i] = cr[t + i * 1024];
    int cell = __float_as_int(mreg[i].w);
    atomicAdd(&hist[cell], 1);
    atomicAdd(&hist[cell + 1024], 1);
  }
  __syncthreads();
  const int base = t * 32;
  int s = 0;
#pragma unroll
  for (int j = 0; j < 32; ++j) s += hist[base + ((j + t) & 31)];
  const int lane = t & 63, wv = t >> 6;
  int sc = s;
#pragma unroll
  for (int off = 1; off < 64; off <<= 1) {
    int x = __shfl_up(sc, off);
    if (lane >= off) sc += x;
  }
  if (lane == 63) wsum[wv] = sc;
  __syncthreads();
  if (t < 16) {
    int x = wsum[t];
    int sc2 = x;
#pragma unroll
    for (int off = 1; off < 16; off <<= 1) {
      int y = __shfl_up(sc2, off);
      if (t >= off) sc2 += y;
    }
    wsum[t] = sc2 - x;
  }
  __syncthreads();
  int run = sc - s + wsum[wv];
#pragma unroll
  for (int j = 0; j < 32; ++j) {
    int idx = base + ((j + t) & 31);
    int v = hist[idx];
    hist[idx] = run;
    run += v;
  }
  __syncthreads();
  // save window boundaries BEFORE scatter mutates hist
  if (t < NWIN_) {
    int wb = t << 7;
    int lc = wb - 33; if (lc < 0) lc = 0;
    wlo[bh * NWIN_ + t] = hist[lc];
    whi[bh * NWIN_ + t] = (t == NWIN_ - 1) ? NPSE_ : hist[wb + 128];
  }
  __syncthreads();
  float4* dst = sorted + (size_t)bh * NPSE_;
  // phase 1: half=0 entries (base cell)
#pragma unroll
  for (int i = 0; i < 8; ++i) {
    int n = t + i * 1024;
    float4 m = mreg[i];
    int cell = __float_as_int(m.w);
    int pos = atomicAdd(&hist[cell], 1);
    m.w = __int_as_float(cell | (n << 15));
    dst[pos] = m;
  }
  __syncthreads();
  // phase 2: half=1 entries (cell+1024)
#pragma unroll
  for (int i = 0; i < 8; ++i) {
    int n = t + i * 1024;
    float4 m = mreg[i];
    int cell = __float_as_int(m.w) + 1024;
    int pos = atomicAdd(&hist[cell], 1);
    m.w = __int_as_float(cell | (n << 15) | (1 << 28));
    dst[pos] = m;
  }
}

// ============================================================
// accum: block = (bh, 128-cell window). lane = feature.
// tile[128][65] = 33 KB -> 4 blocks/CU (~32 waves). Pseudo-
// entries spread only +0..+33 cells (x handled by duplication).
// Broadcast metadata, coalesced 256B value reads, register
// run-merge (key = cell|half), 4 corner accs, flush -> LDS
// atomics; coalesced non-atomic z write + fused occ.
// ============================================================
__global__ __launch_bounds__(512) void accum_kernel(const float* __restrict__ vals,
                                                    const float* __restrict__ scale,
                                                    const float* __restrict__ shift,
                                                    const float4* __restrict__ sorted,
                                                    const int* __restrict__ wlo,
                                                    const int* __restrict__ whi,
                                                    float* __restrict__ zout,
                                                    unsigned int* __restrict__ occ) {
  const int blk = blockIdx.x;          // bh*256 + w
  const int w  = blk & (NWIN_ - 1);
  const int bh = blk >> 8;
  const int h  = bh & 7;
  const int wb = w << 7;
  __shared__ float tile[128 * 65];     // 33.3 KB
  const int t = threadIdx.x;
  for (int i = t; i < 128 * 65; i += 512) tile[i] = 0.f;   // FIXED: full init
  const int lane = t & 63, wv = t >> 6;
  const float sc = scale[24 + h * 64 + lane];
  const float sh = shift[24 + h * 64 + lane];
  const float* vbase = vals + ((size_t)bh << 19);   // bh*8192*64
  const float4* sp = sorted + ((size_t)bh * NPSE_);
  __syncthreads();

  const int lo = wlo[blk], hi = whi[blk];
  const int cnt_e = hi - lo;
  const int chunk = (cnt_e + 7) >> 3;
  const int s0 = lo + wv * chunk;
  const int s1 = min(s0 + chunk, hi);

  float m0 = 0.f, m1 = 0.f, m2 = 0.f, m3 = 0.f;
  int curkey = -1, curbc = 0;

#define FLUSH() {                                                              \
    int tc;                                                                    \
    tc = curbc;    if ((unsigned)tc < 128u) atomicAdd(&tile[tc*65+lane], m0);  \
    tc = curbc+1;  if ((unsigned)tc < 128u) atomicAdd(&tile[tc*65+lane], m1);  \
    tc = curbc+32; if ((unsigned)tc < 128u) atomicAdd(&tile[tc*65+lane], m2);  \
    tc = curbc+33; if ((unsigned)tc < 128u) atomicAdd(&tile[tc*65+lane], m3);  \
  }

  for (int c0 = s0; c0 < s1; c0 += 4) {
    float4 ee[4];
#pragma unroll
    for (int i = 0; i < 4; ++i) {
      int idx = c0 + i; if (idx >= s1) idx = s1 - 1;
      ee[i] = sp[idx];                      // wave-uniform broadcast
    }
    float vv[4];
#pragma unroll
    for (int i = 0; i < 4; ++i) {
      int n = (__float_as_int(ee[i].w) >> 15) & 8191;
      vv[i] = vbase[((size_t)n << 6) + lane];  // coalesced 256B
    }
#pragma unroll
    for (int i = 0; i < 4; ++i) {
      bool live = (c0 + i) < s1;
      int packed = __float_as_int(ee[i].w);
      int key = packed & ((1 << 28) | 32767);   // cell | half
      if (key != curkey) {
        if (curkey >= 0) FLUSH();
        m0 = m1 = m2 = m3 = 0.f;
        curkey = key;
        curbc = (packed & 32767) - wb;
      }
      float v = live ? fmaf(vv[i], sc, sh) : 0.f;
      float r0 = ee[i].x, r1 = ee[i].y, r2 = ee[i].z;
      float vm = v * ((packed >> 28) ? r0 : (1.f - r0));
      float c00 = (1.f - r1) * (1.f - r2), c01 = (1.f - r1) * r2;
      float c10 = r1 * (1.f - r2),         c11 = r1 * r2;
      m0 = fmaf(vm, c00, m0); m1 = fmaf(vm, c01, m1);
      m2 = fmaf(vm, c10, m2); m3 = fmaf(vm, c11, m3);
    }
  }
  if (curkey >= 0) FLUSH();
#undef FLUSH
  __syncthreads();

  unsigned int cnt = 0;
#pragma unroll
  for (int ff = 0; ff < 8; ++ff) {
    int f = wv * 8 + ff;
    float* dst = zout + (((size_t)(bh * 64 + f)) << 15) + wb;
#pragma unroll
    for (int c = 0; c < 2; ++c) {
      int cl = c * 64 + lane;
      float v = tile[cl * 65 + f];
      cnt += (fabsf(v) > 1e-9f) ? 1u : 0u;
      dst[cl] = v;                         // coalesced, non-atomic
    }
  }
#pragma unroll
  for (int off = 32; off; off >>= 1) cnt += __shfl_down(cnt, off);
  __shared__ unsigned int wc[8];
  if (lane == 0) wc[wv] = cnt;
  __syncthreads();
  if (t == 0) {
    unsigned int s = 0;
#pragma unroll
    for (int i = 0; i < 8; ++i) s += wc[i];
    atomicAdd(occ, s);
  }
}

// ============================================================
// fallback path (small ws): fp32 everything, direct splat
// ============================================================
__global__ __launch_bounds__(256) void gemm_full_kernel(const float* __restrict__ W,
                                                        const float* __restrict__ X,
                                                        float* __restrict__ KV) {
  const int n0 = blockIdx.x * 256;
  const int m0 = blockIdx.y * 64;
  const int b  = blockIdx.z;
  __shared__ float Wt[32][68];
  __shared__ float In[32][260];
  const int t  = threadIdx.x;
  const int tx = t & 31;
  const int ty = t >> 5;
  float acc[8][8];
#pragma unroll
  for (int r = 0; r < 8; ++r)
#pragma unroll
    for (int c = 0; c < 8; ++c) acc[r][c] = 0.f;
  const float* Xb = X + (size_t)b * MD_ * N_;
  for (int k0 = 0; k0 < MD_; k0 += 32) {
#pragma unroll
    for (int i = 0; i < 8; ++i) {
      int idx = t + i * 256;
      int m = idx >> 5, k = idx & 31;
      int mm = m0 + m;
      Wt[k][m] = (mm < OC_) ? W[(size_t)mm * MD_ + (k0 + k)] : 0.f;
    }
#pragma unroll
    for (int i = 0; i < 8; ++i) {
      int slot = t + i * 256;
      int k = slot >> 6, n4 = slot & 63;
      float4 v = *(const float4*)(Xb + (size_t)(k0 + k) * N_ + n0 + n4 * 4);
      *(float4*)&In[k][n4 * 4] = v;
    }
    __syncthreads();
#pragma unroll
    for (int k = 0; k < 32; ++k) {
      float a[8], bb[8];
      *(float4*)&a[0]  = *(const float4*)&Wt[k][ty * 8];
      *(float4*)&a[4]  = *(const float4*)&Wt[k][ty * 8 + 4];
      *(float4*)&bb[0] = *(const float4*)&In[k][tx * 4];
      *(float4*)&bb[4] = *(const float4*)&In[k][128 + tx * 4];
#pragma unroll
      for (int r = 0; r < 8; ++r)
#pragma unroll
        for (int c = 0; c < 8; ++c)
          acc[r][c] = fmaf(a[r], bb[c], acc[r][c]);
    }
    __syncthreads();
  }
#pragma unroll
  for (int r = 0; r < 8; ++r) {
    int mm = m0 + ty * 8 + r;
    if (mm < OC_) {
      float* dst = KV + ((size_t)b * OC_ + mm) * N_ + n0;
      *(float4*)(dst + tx * 4)       = *(float4*)&acc[r][0];
      *(float4*)(dst + 128 + tx * 4) = *(float4*)&acc[r][4];
    }
  }
}

__global__ __launch_bounds__(256) void bn_kernel(const float* __restrict__ KV,
                                                 const float* __restrict__ kg,
                                                 const float* __restrict__ kb,
                                                 const float* __restrict__ vg,
                                                 const float* __restrict__ vb,
                                                 float* __restrict__ scale,
                                                 float* __restrict__ shift) {
  const int o = blockIdx.x;
  const int t = threadIdx.x;
  float s = 0.f, s2 = 0.f;
  for (int idx = t; idx < B_ * N_; idx += 256) {
    int bb = idx >> 13, n = idx & (N_ - 1);
    float v = KV[((size_t)bb * OC_ + o) * N_ + n];
    s += v; s2 = fmaf(v, v, s2);
  }
#pragma unroll
  for (int off = 32; off; off >>= 1) {
    s  += __shfl_down(s, off);
    s2 += __shfl_down(s2, off);
  }
  __shared__ float rs[4], rs2[4];
  if ((t & 63) == 0) { rs[t >> 6] = s; rs2[t >> 6] = s2; }
  __syncthreads();
  if (t == 0) {
    s  = rs[0] + rs[1] + rs[2] + rs[3];
    s2 = rs2[0] + rs2[1] + rs2[2] + rs2[3];
    const float inv = 1.0f / (B_ * N_);
    float mu  = s * inv;
    float var = s2 * inv - mu * mu;
    float g, be;
    if (o < 24) { g = kg[o]; be = kb[o]; }
    else        { g = vg[o - 24]; be = vb[o - 24]; }
    float sc = g * rsqrtf(var + 1e-5f);
    scale[o] = sc;
    shift[o] = be - mu * sc;
  }
}

__global__ __launch_bounds__(256) void splat_final_kernel(const float* __restrict__ KV,
                                                          const float* __restrict__ orig,
                                                          const float* __restrict__ proj,
                                                          const float* __restrict__ scale,
                                                          const float* __restrict__ shift,
                                                          float* __restrict__ Z,
                                                          float* __restrict__ kacc) {
  const int bh = blockIdx.x >> 7;
  const int n0 = (blockIdx.x & 127) << 6;
  const int b = bh >> 3, h = bh & 7;
  __shared__ float vals[64][65];
  __shared__ int   cellS[64];
  __shared__ float rS[64][4];
  const int t = threadIdx.x;
  const float* KVb = KV + (size_t)b * OC_ * N_;
  const int ch0 = 24 + h * 64;
#pragma unroll
  for (int i = 0; i < 16; ++i) {
    int idx = t + i * 256;
    int f = idx >> 6, p = idx & 63;
    int ch = ch0 + f;
    vals[f][p] = fmaf(KVb[(size_t)ch * N_ + n0 + p], scale[ch], shift[ch]);
  }
  if (t < 64) {
    const int n = n0 + t;
    float pt[3];
#pragma unroll
    for (int k = 0; k < 3; ++k) {
      int ch = h * 3 + k;
      float kr = fmaf(KVb[(size_t)ch * N_ + n], scale[ch], shift[ch]);
      pt[k] = orig[((size_t)b * 3 + k) * N_ + n] + kr;
    }
    float ksum = 0.f, ksq = 0.f;
    int cell = 0;
    float rr[3];
#pragma unroll
    for (int d = 0; d < 3; ++d) {
      const float* pr = proj + (h * 3 + d) * 3;
      float key = pr[0] * pt[0] + pr[1] * pt[1] + pr[2] * pt[2];
      ksum += key; ksq += key * key;
      float lat = tanhf(key);
      float c = (lat + 1.0f) * 15.5f;
      float fl = floorf(c);
      fl = fminf(fmaxf(fl, 0.0f), 30.0f);
      rr[d] = c - fl;
      cell += (int)fl * ((d == 0) ? 1024 : (d == 1) ? 32 : 1);
    }
    cellS[t] = cell;
    rS[t][0] = rr[0]; rS[t][1] = rr[1]; rS[t][2] = rr[2];
#pragma unroll
    for (int off = 32; off; off >>= 1) {
      ksum += __shfl_down(ksum, off);
      ksq  += __shfl_down(ksq, off);
    }
    if (t == 0) { atomicAdd(&kacc[0], ksum); atomicAdd(&kacc[1], ksq); }
  }
  __syncthreads();
  const int w = t >> 6, l = t & 63;
  for (int pi = 0; pi < 16; ++pi) {
    int p = w * 16 + pi;
    int cell = cellS[p];
    float r0 = rS[p][0], r1 = rS[p][1], r2 = rS[p][2];
    float u0 = 1.f - r0, u1 = 1.f - r1, u2 = 1.f - r2;
    float v = vals[l][p];
#pragma unroll
    for (int c = 0; c < 8; ++c) {
      float wt = ((c & 4) ? r0 : u0) * ((c & 2) ? r1 : u1) * ((c & 1) ? r2 : u2);
      int cc = cell + ((c & 4) ? 1024 : 0) + ((c & 2) ? 32 : 0) + (c & 1);
      atomicAdd(Z + (size_t)(bh * 64 + l) * NC_ + cc, v * wt);
    }
  }
}

__global__ __launch_bounds__(256) void count_kernel(const float* __restrict__ Z,
                                                    unsigned int* __restrict__ occ) {
  unsigned int cnt = 0;
  for (long long i = (long long)blockIdx.x * blockDim.x + threadIdx.x; i < ZTOT_;
       i += (long long)gridDim.x * blockDim.x)
    cnt += (fabsf(Z[i]) > 1e-9f) ? 1u : 0u;
#pragma unroll
  for (int off = 32; off; off >>= 1) cnt += __shfl_down(cnt, off);
  __shared__ unsigned int wc[4];
  const int t = threadIdx.x;
  if ((t & 63) == 0) wc[t >> 6] = cnt;
  __syncthreads();
  if (t == 0) atomicAdd(occ, wc[0] + wc[1] + wc[2] + wc[3]);
}

__global__ void finalize_kernel(const unsigned int* __restrict__ occ,
                                const float* __restrict__ kacc,
                                float* __restrict__ tail) {
  float mean = kacc[0] / NKEYS_;
  tail[0] = (float)(*occ) * (1.0f / 2048.0f);
  tail[1] = mean;
  tail[2] = kacc[1] / NKEYS_ - mean * mean;
}

// ============================================================
extern "C" void kernel_launch(void* const* d_in, const int* in_sizes, int n_in,
                              void* d_out, int out_size, void* d_ws, size_t ws_size,
                              hipStream_t stream) {
  const float* X    = (const float*)d_in[0];
  const float* orig = (const float*)d_in[1];
  const float* W    = (const float*)d_in[2];
  const float* kg   = (const float*)d_in[3];
  const float* kb   = (const float*)d_in[4];
  const float* vg   = (const float*)d_in[5];
  const float* vb   = (const float*)d_in[6];
  const float* proj = (const float*)d_in[7];
  float* out = (float*)d_out;

  float* P = (float*)d_ws;
  float* ssum  = P;                         // [544]
  float* s2sum = P + 544;                   // [544]
  float* kacc  = P + 1088;                  // [2]
  unsigned int* occ = (unsigned int*)(P + 1090);
  float* scale = P + 1152;                  // [536]
  float* shift = P + 1696;                  // [536]
  char* wsb = (char*)d_ws;

  const size_t need = (size_t)80 << 20;
  if (ws_size >= need) {
    unsigned short* Wbf = (unsigned short*)(wsb + 65536);           // 512 KB
    int*    wlo    = (int*)(wsb + ((size_t)1 << 20));               // 32 KB
    int*    whi    = (int*)(wsb + ((size_t)1 << 20) + 65536);       // 32 KB
    float*  kvk    = (float*)(wsb + ((size_t)2 << 20));             // 3 MB
    float4* sorted = (float4*)(wsb + ((size_t)6 << 20));            // 8 MB
    float*  vals   = (float*)(wsb + ((size_t)14 << 20));            // 64 MB -> ends 78MB
    // staging in d_out's z region (consumed before accum writes z)
    unsigned short* Xt = (unsigned short*)out;                      // 32 MB
    float4* cellr = (float4*)((char*)out + ((size_t)48 << 20));     // 4 MB

    hipMemsetAsync(P, 0, 4368, stream);

    convw_kernel<<<256, 256, 0, stream>>>(W, Wbf);
    convxt_kernel<<<dim3(128, 8, 4), 256, 0, stream>>>(X, Xt);
    gemm_keys<<<dim3(32, 4), 256, 0, stream>>>(W, X, kvk, ssum, s2sum);
    gemm_mfma<<<dim3(4, 64, 4), 256, 0, stream>>>(Wbf, Xt, vals, ssum, s2sum);
    bnfin_kernel<<<3, 256, 0, stream>>>(ssum, s2sum, kg, kb, vg, vb, scale, shift);
    passk_kernel<<<NPTS_ / 256, 256, 0, stream>>>(kvk, orig, proj, scale, shift,
                                                  cellr, kacc);
    sortk_kernel<<<32, 1024, 0, stream>>>(cellr, sorted, wlo, whi);
    accum_kernel<<<32 * NWIN_, 512, 0, stream>>>(vals, scale, shift, sorted,
                                                 wlo, whi, out, occ);
    finalize_kernel<<<1, 1, 0, stream>>>(occ, kacc, out + ZTOT_);
  } else {
    float* kv = (float*)(wsb + 16384);
    hipMemsetAsync(P, 0, 4368, stream);
    hipMemsetAsync(out, 0, (size_t)ZTOT_ * 4, stream);
    gemm_full_kernel<<<dim3(N_ / 256, 9, B_), 256, 0, stream>>>(W, X, kv);
    bn_kernel<<<OC_, 256, 0, stream>>>(kv, kg, kb, vg, vb, scale, shift);
    splat_final_kernel<<<B_ * HEADS_ * (N_ / 64), 256, 0, stream>>>(
        kv, orig, proj, scale, shift, out, kacc);
    count_kernel<<<2048, 256, 0, stream>>>(out, occ);
    finalize_kernel<<<1, 1, 0, stream>>>(occ, kacc, out + ZTOT_);
  }
}

// Round 12
// 707.861 us; speedup vs baseline: 1.2757x; 1.2757x over previous
//
#include <hip/hip_runtime.h>

// ---- problem constants ----
#define B_     4
#define N_     8192
#define MD_    512
#define OC_    536        // HEADS*(FEAT+3)
#define HEADS_ 8
#define FEAT_  64
#define NC_    32768      // 32^3 cells
#define ZTOT_  67108864ll // B*HEADS*FEAT*NC
#define NPTS_  262144     // B*HEADS*N
#define NKEYS_ 786432.0f  // B*HEADS*3*N

typedef __bf16 bf16x8 __attribute__((ext_vector_type(8)));
typedef float  f32x4  __attribute__((ext_vector_type(4)));

__device__ __forceinline__ unsigned short f2bf(float f) {
  unsigned int u = __float_as_uint(f);
  u = (u + 0x7FFFu + ((u >> 16) & 1u)) >> 16;   // round-to-nearest-even
  return (unsigned short)u;
}

// ============================================================
// convW: W rows 24..535 -> bf16 [512][512]
// ============================================================
__global__ __launch_bounds__(256) void convw_kernel(const float* __restrict__ W,
                                                    unsigned short* __restrict__ Wbf) {
  int i = (blockIdx.x * 256 + threadIdx.x) * 4;
  float4 v = *(const float4*)&W[24 * 512 + i];
  ushort4 o;
  o.x = f2bf(v.x); o.y = f2bf(v.y); o.z = f2bf(v.z); o.w = f2bf(v.w);
  *(ushort4*)&Wbf[i] = o;
}

// ============================================================
// convXt: X[b][k][n] f32 -> Xt[b][n][k] bf16 (transposed)
// ============================================================
__global__ __launch_bounds__(256) void convxt_kernel(const float* __restrict__ X,
                                                     unsigned short* __restrict__ Xt) {
  const int n0 = blockIdx.x * 64;
  const int k0 = blockIdx.y * 64;
  const int b  = blockIdx.z;
  __shared__ float T[64][65];
  const int t = threadIdx.x;
#pragma unroll
  for (int i = 0; i < 16; ++i) {
    int idx = t + i * 256;
    int kk = idx >> 6, nn = idx & 63;
    T[kk][nn] = X[((size_t)b * MD_ + k0 + kk) * N_ + n0 + nn];
  }
  __syncthreads();
  const int sub = t & 7;
  const int nb  = t >> 3;
#pragma unroll
  for (int i = 0; i < 2; ++i) {
    int nn = nb + i * 32;
    ushort4 o0, o1;
    o0.x = f2bf(T[sub * 8 + 0][nn]); o0.y = f2bf(T[sub * 8 + 1][nn]);
    o0.z = f2bf(T[sub * 8 + 2][nn]); o0.w = f2bf(T[sub * 8 + 3][nn]);
    o1.x = f2bf(T[sub * 8 + 4][nn]); o1.y = f2bf(T[sub * 8 + 5][nn]);
    o1.z = f2bf(T[sub * 8 + 6][nn]); o1.w = f2bf(T[sub * 8 + 7][nn]);
    unsigned short* dst = Xt + ((size_t)b * N_ + n0 + nn) * MD_ + k0 + sub * 8;
    *(ushort4*)dst = o0;
    *(ushort4*)(dst + 4) = o1;
  }
}

// ============================================================
// gemm_keys: fp32-exact GEMM for key channels (rows 0..23 of kv)
// + fused per-channel stats
// ============================================================
__global__ __launch_bounds__(256) void gemm_keys(const float* __restrict__ W,
                                                 const float* __restrict__ X,
                                                 float* __restrict__ KV,
                                                 float* __restrict__ ssum,
                                                 float* __restrict__ s2sum) {
  const int n0 = blockIdx.x * 256;
  const int b  = blockIdx.y;
  __shared__ float Wt[32][26];
  __shared__ float In[32][260];
  const int t  = threadIdx.x;
  const int cg = t & 63;
  const int rb = (t >> 6) * 6;
  float acc[6][4];
#pragma unroll
  for (int r = 0; r < 6; ++r)
#pragma unroll
    for (int c = 0; c < 4; ++c) acc[r][c] = 0.f;
  const float* Xb = X + (size_t)b * MD_ * N_;
  for (int k0 = 0; k0 < MD_; k0 += 32) {
#pragma unroll
    for (int i = 0; i < 3; ++i) {
      int idx = t * 3 + i;
      int m = idx % 24, k = idx / 24;
      Wt[k][m] = W[(size_t)m * MD_ + k0 + k];
    }
#pragma unroll
    for (int i = 0; i < 8; ++i) {
      int slot = t + i * 256;
      int k = slot >> 6, n4 = slot & 63;
      float4 v = *(const float4*)(Xb + (size_t)(k0 + k) * N_ + n0 + n4 * 4);
      *(float4*)&In[k][n4 * 4] = v;
    }
    __syncthreads();
#pragma unroll
    for (int k = 0; k < 32; ++k) {
      float4 bv = *(const float4*)&In[k][cg * 4];
#pragma unroll
      for (int r = 0; r < 6; ++r) {
        float a = Wt[k][rb + r];
        acc[r][0] = fmaf(a, bv.x, acc[r][0]);
        acc[r][1] = fmaf(a, bv.y, acc[r][1]);
        acc[r][2] = fmaf(a, bv.z, acc[r][2]);
        acc[r][3] = fmaf(a, bv.w, acc[r][3]);
      }
    }
    __syncthreads();
  }
#pragma unroll
  for (int r = 0; r < 6; ++r) {
    float* dst = KV + ((size_t)b * OC_ + rb + r) * N_ + n0 + cg * 4;
    *(float4*)dst = *(float4*)&acc[r][0];
    float s = acc[r][0] + acc[r][1] + acc[r][2] + acc[r][3];
    float s2 = acc[r][0]*acc[r][0] + acc[r][1]*acc[r][1] +
               acc[r][2]*acc[r][2] + acc[r][3]*acc[r][3];
#pragma unroll
    for (int off = 32; off; off >>= 1) {
      s  += __shfl_down(s, off);
      s2 += __shfl_down(s2, off);
    }
    if (cg == 0) { atomicAdd(&ssum[rb + r], s); atomicAdd(&s2sum[rb + r], s2); }
  }
}

// ============================================================
// gemm_mfma: bf16 MFMA GEMM for value channels (kv rows 24..535)
// + fused per-channel stats.  BM=BN=128, BK=64, 4 waves.
// ============================================================
__global__ __launch_bounds__(256) void gemm_mfma(const unsigned short* __restrict__ Wbf,
                                                 const unsigned short* __restrict__ Xt,
                                                 float* __restrict__ KV,
                                                 float* __restrict__ ssum,
                                                 float* __restrict__ s2sum) {
  const int m0 = blockIdx.x * 128;
  const int n0 = blockIdx.y * 128;
  const int b  = blockIdx.z;
  __shared__ __align__(16) unsigned short Al[128][72];
  __shared__ __align__(16) unsigned short Bl[128][72];
  const int t = threadIdx.x;
  const int lane = t & 63, wave = t >> 6;
  const int wm = wave >> 1, wn = wave & 1;
  f32x4 acc[4][4];
#pragma unroll
  for (int mi = 0; mi < 4; ++mi)
#pragma unroll
    for (int ni = 0; ni < 4; ++ni)
#pragma unroll
      for (int j = 0; j < 4; ++j) acc[mi][ni][j] = 0.f;

  const unsigned short* Xb = Xt + ((size_t)b * N_ + n0) * MD_;
  for (int k0 = 0; k0 < MD_; k0 += 64) {
#pragma unroll
    for (int i = 0; i < 4; ++i) {
      int chunk = t + i * 256;
      int r = chunk >> 3, c = chunk & 7;
      *(uint4*)&Al[r][c * 8] =
          *(const uint4*)&Wbf[(size_t)(m0 + r) * MD_ + k0 + c * 8];
    }
#pragma unroll
    for (int i = 0; i < 4; ++i) {
      int chunk = t + i * 256;
      int r = chunk >> 3, c = chunk & 7;
      *(uint4*)&Bl[r][c * 8] =
          *(const uint4*)&Xb[(size_t)r * MD_ + k0 + c * 8];
    }
    __syncthreads();
#pragma unroll
    for (int ks = 0; ks < 2; ++ks) {
      bf16x8 af[4], bfr[4];
#pragma unroll
      for (int mi = 0; mi < 4; ++mi)
        af[mi] = *(const bf16x8*)&Al[wm * 64 + mi * 16 + (lane & 15)]
                                    [ks * 32 + (lane >> 4) * 8];
#pragma unroll
      for (int ni = 0; ni < 4; ++ni)
        bfr[ni] = *(const bf16x8*)&Bl[wn * 64 + ni * 16 + (lane & 15)]
                                     [ks * 32 + (lane >> 4) * 8];
#pragma unroll
      for (int mi = 0; mi < 4; ++mi)
#pragma unroll
        for (int ni = 0; ni < 4; ++ni)
          acc[mi][ni] = __builtin_amdgcn_mfma_f32_16x16x32_bf16(
              af[mi], bfr[ni], acc[mi][ni], 0, 0, 0);
    }
    __syncthreads();
  }
  // fused stats
#pragma unroll
  for (int mi = 0; mi < 4; ++mi)
#pragma unroll
    for (int j = 0; j < 4; ++j) {
      float s  = acc[mi][0][j] + acc[mi][1][j] + acc[mi][2][j] + acc[mi][3][j];
      float s2 = acc[mi][0][j]*acc[mi][0][j] + acc[mi][1][j]*acc[mi][1][j] +
                 acc[mi][2][j]*acc[mi][2][j] + acc[mi][3][j]*acc[mi][3][j];
#pragma unroll
      for (int off = 1; off < 16; off <<= 1) {
        s  += __shfl_xor(s, off);
        s2 += __shfl_xor(s2, off);
      }
      if ((lane & 15) == 0) {
        int mg = m0 + wm * 64 + mi * 16 + (lane >> 4) * 4 + j;
        atomicAdd(&ssum[24 + mg], s);
        atomicAdd(&s2sum[24 + mg], s2);
      }
    }
  // write to kv rows 24..535 (row-major, R6 layout)
#pragma unroll
  for (int mi = 0; mi < 4; ++mi) {
#pragma unroll
    for (int ni = 0; ni < 4; ++ni) {
      int m = m0 + wm * 64 + mi * 16 + (lane >> 4) * 4;
      int n = n0 + wn * 64 + ni * 16 + (lane & 15);
#pragma unroll
      for (int j = 0; j < 4; ++j)
        KV[((size_t)b * OC_ + 24 + m + j) * N_ + n] = acc[mi][ni][j];
    }
  }
}

// ============================================================
// bnfin: finalize BN -> scale/shift per channel
// ============================================================
__global__ __launch_bounds__(256) void bnfin_kernel(const float* __restrict__ ssum,
                                                    const float* __restrict__ s2sum,
                                                    const float* __restrict__ kg,
                                                    const float* __restrict__ kb,
                                                    const float* __restrict__ vg,
                                                    const float* __restrict__ vb,
                                                    float* __restrict__ scale,
                                                    float* __restrict__ shift) {
  const int o = blockIdx.x * 256 + threadIdx.x;
  if (o >= OC_) return;
  const float inv = 1.0f / (B_ * N_);
  float mu  = ssum[o] * inv;
  float var = s2sum[o] * inv - mu * mu;
  float g, be;
  if (o < 24) { g = kg[o]; be = kb[o]; }
  else        { g = vg[o - 24]; be = vb[o - 24]; }
  float sc = g * rsqrtf(var + 1e-5f);
  scale[o] = sc;
  shift[o] = be - mu * sc;
}

// ============================================================
// passk: per-point keys -> {r0,r1,r2, cell} + keys mean/var
// ============================================================
__global__ __launch_bounds__(256) void passk_kernel(const float* __restrict__ KV,
                                                    const float* __restrict__ orig,
                                                    const float* __restrict__ proj,
                                                    const float* __restrict__ scale,
                                                    const float* __restrict__ shift,
                                                    float4* __restrict__ cellr,
                                                    float* __restrict__ kacc) {
  const int p = blockIdx.x * 256 + threadIdx.x;
  const int bh = p >> 13, n = p & (N_ - 1);
  const int b = bh >> 3, h = bh & 7;
  const float* KVb = KV + (size_t)b * OC_ * N_;
  float pt[3];
#pragma unroll
  for (int k = 0; k < 3; ++k) {
    int ch = h * 3 + k;
    float kr = fmaf(KVb[(size_t)ch * N_ + n], scale[ch], shift[ch]);
    pt[k] = orig[((size_t)b * 3 + k) * N_ + n] + kr;
  }
  float ksum = 0.f, ksq = 0.f;
  int cell = 0;
  float rr[3];
#pragma unroll
  for (int d = 0; d < 3; ++d) {
    const float* pr = proj + (h * 3 + d) * 3;
    float key = pr[0] * pt[0] + pr[1] * pt[1] + pr[2] * pt[2];
    ksum += key; ksq += key * key;
    float lat = tanhf(key);
    float c = (lat + 1.0f) * 15.5f;
    float fl = floorf(c);
    fl = fminf(fmaxf(fl, 0.0f), 30.0f);
    rr[d] = c - fl;
    cell += (int)fl * ((d == 0) ? 1024 : (d == 1) ? 32 : 1);
  }
  cellr[p] = make_float4(rr[0], rr[1], rr[2], __int_as_float(cell));
#pragma unroll
  for (int off = 32; off; off >>= 1) {
    ksum += __shfl_down(ksum, off);
    ksq  += __shfl_down(ksq, off);
  }
  if ((threadIdx.x & 63) == 0) {
    atomicAdd(&kacc[0], ksum);
    atomicAdd(&kacc[1], ksq);
  }
}

// ============================================================
// sortk: per-bh counting sort of points by cell (R6 version).
// Output: sorted[bh][i] = {r0,r1,r2, bitcast(cell | n<<15)}
// ============================================================
__global__ __launch_bounds__(1024, 1) void sortk_kernel(const float4* __restrict__ cellr,
                                                        float4* __restrict__ sorted) {
  const int bh = blockIdx.x;
  __shared__ int hist[NC_];      // 128 KiB
  __shared__ int wsum[16];
  const int t = threadIdx.x;
  for (int i = t; i < NC_; i += 1024) hist[i] = 0;
  __syncthreads();
  const float4* cr = cellr + (size_t)bh * N_;
#pragma unroll
  for (int i = 0; i < 8; ++i) {
    int cell = __float_as_int(cr[t + i * 1024].w);
    atomicAdd(&hist[cell], 1);
  }
  __syncthreads();
  const int base = t * 32;
  int s = 0;
#pragma unroll
  for (int j = 0; j < 32; ++j) s += hist[base + ((j + t) & 31)];
  const int lane = t & 63, wv = t >> 6;
  int sc = s;
#pragma unroll
  for (int off = 1; off < 64; off <<= 1) {
    int x = __shfl_up(sc, off);
    if (lane >= off) sc += x;
  }
  if (lane == 63) wsum[wv] = sc;
  __syncthreads();
  if (t < 16) {
    int x = wsum[t];
    int sc2 = x;
#pragma unroll
    for (int off = 1; off < 16; off <<= 1) {
      int y = __shfl_up(sc2, off);
      if (t >= off) sc2 += y;
    }
    wsum[t] = sc2 - x;
  }
  __syncthreads();
  int run = sc - s + wsum[wv];
#pragma unroll
  for (int j = 0; j < 32; ++j) {
    int idx = base + ((j + t) & 31);
    int v = hist[idx];
    hist[idx] = run;
    run += v;
  }
  __syncthreads();
  float4* dst = sorted + (size_t)bh * N_;
#pragma unroll
  for (int i = 0; i < 8; ++i) {
    int n = t + i * 1024;
    float4 m = cr[n];
    int cell = __float_as_int(m.w);
    int pos = atomicAdd(&hist[cell], 1);
    m.w = __int_as_float(cell | (n << 15));
    dst[pos] = m;
  }
}

// ============================================================
// accum (R6 structure, 1024 threads): block = (bh, feat), full
// 32^3 grid in 128 KiB LDS. Each THREAD owns 8 consecutive
// sorted entries, merges equal-cell runs in REGISTERS, touches
// the LDS atomic pipe only once per run. 16 waves/block for
// latency hiding. Coalesced non-atomic z write + fused occ.
// ============================================================
__global__ __launch_bounds__(1024, 1) void accum_kernel(const float* __restrict__ KV,
                                                        const float* __restrict__ scale,
                                                        const float* __restrict__ shift,
                                                        const float4* __restrict__ sorted,
                                                        float* __restrict__ zout,
                                                        unsigned int* __restrict__ occ) {
  const int blk = blockIdx.x;       // bh*64 + f
  const int f   = blk & 63;
  const int bh  = blk >> 6;
  const int b = bh >> 3, h = bh & 7;
  __shared__ float tile[NC_];       // 128 KiB
  const int t = threadIdx.x;
#pragma unroll
  for (int i = 0; i < 8; ++i)
    ((float4*)tile)[t + i * 1024] = make_float4(0.f, 0.f, 0.f, 0.f);
  __syncthreads();

  const int ch = 24 + h * 64 + f;
  const float sc = scale[ch], sh = shift[ch];
  const float* kvrow = KV + ((size_t)b * OC_ + ch) * N_;
  const float4* sp = sorted + (size_t)bh * N_;
  const int base = t * 8;

  // prefetch 8 entries + 8 kv gathers (independent loads)
  float4 e[8];
#pragma unroll
  for (int i = 0; i < 8; ++i) e[i] = sp[base + i];
  float kvv[8];
#pragma unroll
  for (int i = 0; i < 8; ++i)
    kvv[i] = kvrow[((unsigned)__float_as_int(e[i].w)) >> 15];

#define FLUSH()                                                     \
  {                                                                 \
    atomicAdd(&tile[cur],        m0_);                              \
    atomicAdd(&tile[cur + 1],    m1_);                              \
    atomicAdd(&tile[cur + 32],   m2_);                              \
    atomicAdd(&tile[cur + 33],   m3_);                              \
    atomicAdd(&tile[cur + 1024], m4_);                              \
    atomicAdd(&tile[cur + 1025], m5_);                              \
    atomicAdd(&tile[cur + 1056], m6_);                              \
    atomicAdd(&tile[cur + 1057], m7_);                              \
  }

  float m0_ = 0.f, m1_ = 0.f, m2_ = 0.f, m3_ = 0.f;
  float m4_ = 0.f, m5_ = 0.f, m6_ = 0.f, m7_ = 0.f;
  int cur = __float_as_int(e[0].w) & 32767;
#pragma unroll
  for (int i = 0; i < 8; ++i) {
    int cell = __float_as_int(e[i].w) & 32767;
    if (cell != cur) {
      FLUSH();
      m0_ = m1_ = m2_ = m3_ = m4_ = m5_ = m6_ = m7_ = 0.f;
      cur = cell;
    }
    float v  = fmaf(kvv[i], sc, sh);
    float r0 = e[i].x, r1 = e[i].y, r2 = e[i].z;
    float va = v * (1.f - r0), vb = v * r0;
    float c00 = (1.f - r1) * (1.f - r2), c01 = (1.f - r1) * r2;
    float c10 = r1 * (1.f - r2),         c11 = r1 * r2;
    m0_ = fmaf(va, c00, m0_); m1_ = fmaf(va, c01, m1_);
    m2_ = fmaf(va, c10, m2_); m3_ = fmaf(va, c11, m3_);
    m4_ = fmaf(vb, c00, m4_); m5_ = fmaf(vb, c01, m5_);
    m6_ = fmaf(vb, c10, m6_); m7_ = fmaf(vb, c11, m7_);
  }
  FLUSH();
#undef FLUSH
  __syncthreads();

  unsigned int cnt = 0;
  float* dst = zout + (size_t)blk * NC_;
#pragma unroll
  for (int i = 0; i < 8; ++i) {
    float4 v = ((const float4*)tile)[t + i * 1024];
    cnt += (fabsf(v.x) > 1e-9f) ? 1u : 0u;
    cnt += (fabsf(v.y) > 1e-9f) ? 1u : 0u;
    cnt += (fabsf(v.z) > 1e-9f) ? 1u : 0u;
    cnt += (fabsf(v.w) > 1e-9f) ? 1u : 0u;
    ((float4*)dst)[t + i * 1024] = v;
  }
#pragma unroll
  for (int off = 32; off; off >>= 1) cnt += __shfl_down(cnt, off);
  __shared__ unsigned int wc[16];
  if ((t & 63) == 0) wc[t >> 6] = cnt;
  __syncthreads();
  if (t == 0) {
    unsigned int s = 0;
#pragma unroll
    for (int i = 0; i < 16; ++i) s += wc[i];
    atomicAdd(occ, s);
  }
}

// ============================================================
// fallback path (small ws): fp32 everything, direct splat
// ============================================================
__global__ __launch_bounds__(256) void gemm_full_kernel(const float* __restrict__ W,
                                                        const float* __restrict__ X,
                                                        float* __restrict__ KV) {
  const int n0 = blockIdx.x * 256;
  const int m0 = blockIdx.y * 64;
  const int b  = blockIdx.z;
  __shared__ float Wt[32][68];
  __shared__ float In[32][260];
  const int t  = threadIdx.x;
  const int tx = t & 31;
  const int ty = t >> 5;
  float acc[8][8];
#pragma unroll
  for (int r = 0; r < 8; ++r)
#pragma unroll
    for (int c = 0; c < 8; ++c) acc[r][c] = 0.f;
  const float* Xb = X + (size_t)b * MD_ * N_;
  for (int k0 = 0; k0 < MD_; k0 += 32) {
#pragma unroll
    for (int i = 0; i < 8; ++i) {
      int idx = t + i * 256;
      int m = idx >> 5, k = idx & 31;
      int mm = m0 + m;
      Wt[k][m] = (mm < OC_) ? W[(size_t)mm * MD_ + (k0 + k)] : 0.f;
    }
#pragma unroll
    for (int i = 0; i < 8; ++i) {
      int slot = t + i * 256;
      int k = slot >> 6, n4 = slot & 63;
      float4 v = *(const float4*)(Xb + (size_t)(k0 + k) * N_ + n0 + n4 * 4);
      *(float4*)&In[k][n4 * 4] = v;
    }
    __syncthreads();
#pragma unroll
    for (int k = 0; k < 32; ++k) {
      float a[8], bb[8];
      *(float4*)&a[0]  = *(const float4*)&Wt[k][ty * 8];
      *(float4*)&a[4]  = *(const float4*)&Wt[k][ty * 8 + 4];
      *(float4*)&bb[0] = *(const float4*)&In[k][tx * 4];
      *(float4*)&bb[4] = *(const float4*)&In[k][128 + tx * 4];
#pragma unroll
      for (int r = 0; r < 8; ++r)
#pragma unroll
        for (int c = 0; c < 8; ++c)
          acc[r][c] = fmaf(a[r], bb[c], acc[r][c]);
    }
    __syncthreads();
  }
#pragma unroll
  for (int r = 0; r < 8; ++r) {
    int mm = m0 + ty * 8 + r;
    if (mm < OC_) {
      float* dst = KV + ((size_t)b * OC_ + mm) * N_ + n0;
      *(float4*)(dst + tx * 4)       = *(float4*)&acc[r][0];
      *(float4*)(dst + 128 + tx * 4) = *(float4*)&acc[r][4];
    }
  }
}

__global__ __launch_bounds__(256) void bn_kernel(const float* __restrict__ KV,
                                                 const float* __restrict__ kg,
                                                 const float* __restrict__ kb,
                                                 const float* __restrict__ vg,
                                                 const float* __restrict__ vb,
                                                 float* __restrict__ scale,
                                                 float* __restrict__ shift) {
  const int o = blockIdx.x;
  const int t = threadIdx.x;
  float s = 0.f, s2 = 0.f;
  for (int idx = t; idx < B_ * N_; idx += 256) {
    int bb = idx >> 13, n = idx & (N_ - 1);
    float v = KV[((size_t)bb * OC_ + o) * N_ + n];
    s += v; s2 = fmaf(v, v, s2);
  }
#pragma unroll
  for (int off = 32; off; off >>= 1) {
    s  += __shfl_down(s, off);
    s2 += __shfl_down(s2, off);
  }
  __shared__ float rs[4], rs2[4];
  if ((t & 63) == 0) { rs[t >> 6] = s; rs2[t >> 6] = s2; }
  __syncthreads();
  if (t == 0) {
    s  = rs[0] + rs[1] + rs[2] + rs[3];
    s2 = rs2[0] + rs2[1] + rs2[2] + rs2[3];
    const float inv = 1.0f / (B_ * N_);
    float mu  = s * inv;
    float var = s2 * inv - mu * mu;
    float g, be;
    if (o < 24) { g = kg[o]; be = kb[o]; }
    else        { g = vg[o - 24]; be = vb[o - 24]; }
    float sc = g * rsqrtf(var + 1e-5f);
    scale[o] = sc;
    shift[o] = be - mu * sc;
  }
}

__global__ __launch_bounds__(256) void splat_final_kernel(const float* __restrict__ KV,
                                                          const float* __restrict__ orig,
                                                          const float* __restrict__ proj,
                                                          const float* __restrict__ scale,
                                                          const float* __restrict__ shift,
                                                          float* __restrict__ Z,
                                                          float* __restrict__ kacc) {
  const int bh = blockIdx.x >> 7;
  const int n0 = (blockIdx.x & 127) << 6;
  const int b = bh >> 3, h = bh & 7;
  __shared__ float vals[64][65];
  __shared__ int   cellS[64];
  __shared__ float rS[64][4];
  const int t = threadIdx.x;
  const float* KVb = KV + (size_t)b * OC_ * N_;
  const int ch0 = 24 + h * 64;
#pragma unroll
  for (int i = 0; i < 16; ++i) {
    int idx = t + i * 256;
    int f = idx >> 6, p = idx & 63;
    int ch = ch0 + f;
    vals[f][p] = fmaf(KVb[(size_t)ch * N_ + n0 + p], scale[ch], shift[ch]);
  }
  if (t < 64) {
    const int n = n0 + t;
    float pt[3];
#pragma unroll
    for (int k = 0; k < 3; ++k) {
      int ch = h * 3 + k;
      float kr = fmaf(KVb[(size_t)ch * N_ + n], scale[ch], shift[ch]);
      pt[k] = orig[((size_t)b * 3 + k) * N_ + n] + kr;
    }
    float ksum = 0.f, ksq = 0.f;
    int cell = 0;
    float rr[3];
#pragma unroll
    for (int d = 0; d < 3; ++d) {
      const float* pr = proj + (h * 3 + d) * 3;
      float key = pr[0] * pt[0] + pr[1] * pt[1] + pr[2] * pt[2];
      ksum += key; ksq += key * key;
      float lat = tanhf(key);
      float c = (lat + 1.0f) * 15.5f;
      float fl = floorf(c);
      fl = fminf(fmaxf(fl, 0.0f), 30.0f);
      rr[d] = c - fl;
      cell += (int)fl * ((d == 0) ? 1024 : (d == 1) ? 32 : 1);
    }
    cellS[t] = cell;
    rS[t][0] = rr[0]; rS[t][1] = rr[1]; rS[t][2] = rr[2];
#pragma unroll
    for (int off = 32; off; off >>= 1) {
      ksum += __shfl_down(ksum, off);
      ksq  += __shfl_down(ksq, off);
    }
    if (t == 0) { atomicAdd(&kacc[0], ksum); atomicAdd(&kacc[1], ksq); }
  }
  __syncthreads();
  const int w = t >> 6, l = t & 63;
  for (int pi = 0; pi < 16; ++pi) {
    int p = w * 16 + pi;
    int cell = cellS[p];
    float r0 = rS[p][0], r1 = rS[p][1], r2 = rS[p][2];
    float u0 = 1.f - r0, u1 = 1.f - r1, u2 = 1.f - r2;
    float v = vals[l][p];
#pragma unroll
    for (int c = 0; c < 8; ++c) {
      float wt = ((c & 4) ? r0 : u0) * ((c & 2) ? r1 : u1) * ((c & 1) ? r2 : u2);
      int cc = cell + ((c & 4) ? 1024 : 0) + ((c & 2) ? 32 : 0) + (c & 1);
      atomicAdd(Z + (size_t)(bh * 64 + l) * NC_ + cc, v * wt);
    }
  }
}

__global__ __launch_bounds__(256) void count_kernel(const float* __restrict__ Z,
                                                    unsigned int* __restrict__ occ) {
  unsigned int cnt = 0;
  for (long long i = (long long)blockIdx.x * blockDim.x + threadIdx.x; i < ZTOT_;
       i += (long long)gridDim.x * blockDim.x)
    cnt += (fabsf(Z[i]) > 1e-9f) ? 1u : 0u;
#pragma unroll
  for (int off = 32; off; off >>= 1) cnt += __shfl_down(cnt, off);
  __shared__ unsigned int wc[4];
  const int t = threadIdx.x;
  if ((t & 63) == 0) wc[t >> 6] = cnt;
  __syncthreads();
  if (t == 0) atomicAdd(occ, wc[0] + wc[1] + wc[2] + wc[3]);
}

__global__ void finalize_kernel(const unsigned int* __restrict__ occ,
                                const float* __restrict__ kacc,
                                float* __restrict__ tail) {
  float mean = kacc[0] / NKEYS_;
  tail[0] = (float)(*occ) * (1.0f / 2048.0f);
  tail[1] = mean;
  tail[2] = kacc[1] / NKEYS_ - mean * mean;
}

// ============================================================
extern "C" void kernel_launch(void* const* d_in, const int* in_sizes, int n_in,
                              void* d_out, int out_size, void* d_ws, size_t ws_size,
                              hipStream_t stream) {
  const float* X    = (const float*)d_in[0];
  const float* orig = (const float*)d_in[1];
  const float* W    = (const float*)d_in[2];
  const float* kg   = (const float*)d_in[3];
  const float* kb   = (const float*)d_in[4];
  const float* vg   = (const float*)d_in[5];
  const float* vb   = (const float*)d_in[6];
  const float* proj = (const float*)d_in[7];
  float* out = (float*)d_out;

  float* P = (float*)d_ws;
  float* ssum  = P;                         // [544]
  float* s2sum = P + 544;                   // [544]
  float* kacc  = P + 1088;                  // [2]
  unsigned int* occ = (unsigned int*)(P + 1090);
  float* scale = P + 1152;                  // [536]
  float* shift = P + 1696;                  // [536]
  char* wsb = (char*)d_ws;

  const size_t need = (size_t)80 << 20;
  if (ws_size >= need) {
    unsigned short* Wbf = (unsigned short*)(wsb + 65536);           // 512 KB
    float4* sorted = (float4*)(wsb + ((size_t)1 << 20));            // 4 MB
    float*  kv     = (float*)(wsb + ((size_t)6 << 20));             // 70.3 MB -> ends 76.3MB
    // staging in d_out's z region (consumed before accum writes z)
    unsigned short* Xt = (unsigned short*)out;                      // 32 MB
    float4* cellr = (float4*)((char*)out + ((size_t)48 << 20));     // 4 MB

    hipMemsetAsync(P, 0, 4368, stream);

    convw_kernel<<<256, 256, 0, stream>>>(W, Wbf);
    convxt_kernel<<<dim3(128, 8, 4), 256, 0, stream>>>(X, Xt);
    gemm_keys<<<dim3(32, 4), 256, 0, stream>>>(W, X, kv, ssum, s2sum);
    gemm_mfma<<<dim3(4, 64, 4), 256, 0, stream>>>(Wbf, Xt, kv, ssum, s2sum);
    bnfin_kernel<<<3, 256, 0, stream>>>(ssum, s2sum, kg, kb, vg, vb, scale, shift);
    passk_kernel<<<NPTS_ / 256, 256, 0, stream>>>(kv, orig, proj, scale, shift,
                                                  cellr, kacc);
    sortk_kernel<<<32, 1024, 0, stream>>>(cellr, sorted);
    accum_kernel<<<2048, 1024, 0, stream>>>(kv, scale, shift, sorted, out, occ);
    finalize_kernel<<<1, 1, 0, stream>>>(occ, kacc, out + ZTOT_);
  } else {
    float* kv = (float*)(wsb + 16384);
    hipMemsetAsync(P, 0, 4368, stream);
    hipMemsetAsync(out, 0, (size_t)ZTOT_ * 4, stream);
    gemm_full_kernel<<<dim3(N_ / 256, 9, B_), 256, 0, stream>>>(W, X, kv);
    bn_kernel<<<OC_, 256, 0, stream>>>(kv, kg, kb, vg, vb, scale, shift);
    splat_final_kernel<<<B_ * HEADS_ * (N_ / 64), 256, 0, stream>>>(
        kv, orig, proj, scale, shift, out, kacc);
    count_kernel<<<2048, 256, 0, stream>>>(out, occ);
    finalize_kernel<<<1, 1, 0, stream>>>(occ, kacc, out + ZTOT_);
  }
}

// Round 13
// 601.717 us; speedup vs baseline: 1.5007x; 1.1764x over previous
//
#include <hip/hip_runtime.h>

// ---- problem constants ----
#define B_     4
#define N_     8192
#define MD_    512
#define OC_    536        // HEADS*(FEAT+3)
#define HEADS_ 8
#define FEAT_  64
#define NC_    32768      // 32^3 cells
#define ZTOT_  67108864ll // B*HEADS*FEAT*NC
#define NPTS_  262144     // B*HEADS*N
#define NKEYS_ 786432.0f  // B*HEADS*3*N

typedef __bf16 bf16x8 __attribute__((ext_vector_type(8)));
typedef float  f32x4  __attribute__((ext_vector_type(4)));

__device__ __forceinline__ unsigned short f2bf(float f) {
  unsigned int u = __float_as_uint(f);
  u = (u + 0x7FFFu + ((u >> 16) & 1u)) >> 16;   // round-to-nearest-even
  return (unsigned short)u;
}
__device__ __forceinline__ float bf2f(unsigned short s) {
  return __uint_as_float(((unsigned)s) << 16);
}

// ============================================================
// convW: W rows 24..535 -> bf16 [512][512]
// ============================================================
__global__ __launch_bounds__(256) void convw_kernel(const float* __restrict__ W,
                                                    unsigned short* __restrict__ Wbf) {
  int i = (blockIdx.x * 256 + threadIdx.x) * 4;
  float4 v = *(const float4*)&W[24 * 512 + i];
  ushort4 o;
  o.x = f2bf(v.x); o.y = f2bf(v.y); o.z = f2bf(v.z); o.w = f2bf(v.w);
  *(ushort4*)&Wbf[i] = o;
}

// ============================================================
// convXt: X[b][k][n] f32 -> Xt[b][n][k] bf16 (transposed)
// ============================================================
__global__ __launch_bounds__(256) void convxt_kernel(const float* __restrict__ X,
                                                     unsigned short* __restrict__ Xt) {
  const int n0 = blockIdx.x * 64;
  const int k0 = blockIdx.y * 64;
  const int b  = blockIdx.z;
  __shared__ float T[64][65];
  const int t = threadIdx.x;
#pragma unroll
  for (int i = 0; i < 16; ++i) {
    int idx = t + i * 256;
    int kk = idx >> 6, nn = idx & 63;
    T[kk][nn] = X[((size_t)b * MD_ + k0 + kk) * N_ + n0 + nn];
  }
  __syncthreads();
  const int sub = t & 7;
  const int nb  = t >> 3;
#pragma unroll
  for (int i = 0; i < 2; ++i) {
    int nn = nb + i * 32;
    ushort4 o0, o1;
    o0.x = f2bf(T[sub * 8 + 0][nn]); o0.y = f2bf(T[sub * 8 + 1][nn]);
    o0.z = f2bf(T[sub * 8 + 2][nn]); o0.w = f2bf(T[sub * 8 + 3][nn]);
    o1.x = f2bf(T[sub * 8 + 4][nn]); o1.y = f2bf(T[sub * 8 + 5][nn]);
    o1.z = f2bf(T[sub * 8 + 6][nn]); o1.w = f2bf(T[sub * 8 + 7][nn]);
    unsigned short* dst = Xt + ((size_t)b * N_ + n0 + nn) * MD_ + k0 + sub * 8;
    *(ushort4*)dst = o0;
    *(ushort4*)(dst + 4) = o1;
  }
}

// ============================================================
// gemm_keys: fp32-exact GEMM for key channels -> kvk[b][24][N]
// + fused per-channel stats
// ============================================================
__global__ __launch_bounds__(256) void gemm_keys(const float* __restrict__ W,
                                                 const float* __restrict__ X,
                                                 float* __restrict__ kvk,
                                                 float* __restrict__ ssum,
                                                 float* __restrict__ s2sum) {
  const int n0 = blockIdx.x * 256;
  const int b  = blockIdx.y;
  __shared__ float Wt[32][26];
  __shared__ float In[32][260];
  const int t  = threadIdx.x;
  const int cg = t & 63;
  const int rb = (t >> 6) * 6;
  float acc[6][4];
#pragma unroll
  for (int r = 0; r < 6; ++r)
#pragma unroll
    for (int c = 0; c < 4; ++c) acc[r][c] = 0.f;
  const float* Xb = X + (size_t)b * MD_ * N_;
  for (int k0 = 0; k0 < MD_; k0 += 32) {
#pragma unroll
    for (int i = 0; i < 3; ++i) {
      int idx = t * 3 + i;
      int m = idx % 24, k = idx / 24;
      Wt[k][m] = W[(size_t)m * MD_ + k0 + k];
    }
#pragma unroll
    for (int i = 0; i < 8; ++i) {
      int slot = t + i * 256;
      int k = slot >> 6, n4 = slot & 63;
      float4 v = *(const float4*)(Xb + (size_t)(k0 + k) * N_ + n0 + n4 * 4);
      *(float4*)&In[k][n4 * 4] = v;
    }
    __syncthreads();
#pragma unroll
    for (int k = 0; k < 32; ++k) {
      float4 bv = *(const float4*)&In[k][cg * 4];
#pragma unroll
      for (int r = 0; r < 6; ++r) {
        float a = Wt[k][rb + r];
        acc[r][0] = fmaf(a, bv.x, acc[r][0]);
        acc[r][1] = fmaf(a, bv.y, acc[r][1]);
        acc[r][2] = fmaf(a, bv.z, acc[r][2]);
        acc[r][3] = fmaf(a, bv.w, acc[r][3]);
      }
    }
    __syncthreads();
  }
#pragma unroll
  for (int r = 0; r < 6; ++r) {
    float* dst = kvk + ((size_t)b * 24 + rb + r) * N_ + n0 + cg * 4;
    *(float4*)dst = *(float4*)&acc[r][0];
    float s = acc[r][0] + acc[r][1] + acc[r][2] + acc[r][3];
    float s2 = acc[r][0]*acc[r][0] + acc[r][1]*acc[r][1] +
               acc[r][2]*acc[r][2] + acc[r][3]*acc[r][3];
#pragma unroll
    for (int off = 32; off; off >>= 1) {
      s  += __shfl_down(s, off);
      s2 += __shfl_down(s2, off);
    }
    if (cg == 0) { atomicAdd(&ssum[rb + r], s); atomicAdd(&s2sum[rb + r], s2); }
  }
}

// ============================================================
// gemm_mfma: bf16 MFMA GEMM for value channels -> valsbf
// [b][512][N] bf16 (un-BN'd) + fused fp32 per-channel stats.
// ============================================================
__global__ __launch_bounds__(256) void gemm_mfma(const unsigned short* __restrict__ Wbf,
                                                 const unsigned short* __restrict__ Xt,
                                                 unsigned short* __restrict__ valsbf,
                                                 float* __restrict__ ssum,
                                                 float* __restrict__ s2sum) {
  const int m0 = blockIdx.x * 128;
  const int n0 = blockIdx.y * 128;
  const int b  = blockIdx.z;
  __shared__ __align__(16) unsigned short Al[128][72];
  __shared__ __align__(16) unsigned short Bl[128][72];
  const int t = threadIdx.x;
  const int lane = t & 63, wave = t >> 6;
  const int wm = wave >> 1, wn = wave & 1;
  f32x4 acc[4][4];
#pragma unroll
  for (int mi = 0; mi < 4; ++mi)
#pragma unroll
    for (int ni = 0; ni < 4; ++ni)
#pragma unroll
      for (int j = 0; j < 4; ++j) acc[mi][ni][j] = 0.f;

  const unsigned short* Xb = Xt + ((size_t)b * N_ + n0) * MD_;
  for (int k0 = 0; k0 < MD_; k0 += 64) {
#pragma unroll
    for (int i = 0; i < 4; ++i) {
      int chunk = t + i * 256;
      int r = chunk >> 3, c = chunk & 7;
      *(uint4*)&Al[r][c * 8] =
          *(const uint4*)&Wbf[(size_t)(m0 + r) * MD_ + k0 + c * 8];
    }
#pragma unroll
    for (int i = 0; i < 4; ++i) {
      int chunk = t + i * 256;
      int r = chunk >> 3, c = chunk & 7;
      *(uint4*)&Bl[r][c * 8] =
          *(const uint4*)&Xb[(size_t)r * MD_ + k0 + c * 8];
    }
    __syncthreads();
#pragma unroll
    for (int ks = 0; ks < 2; ++ks) {
      bf16x8 af[4], bfr[4];
#pragma unroll
      for (int mi = 0; mi < 4; ++mi)
        af[mi] = *(const bf16x8*)&Al[wm * 64 + mi * 16 + (lane & 15)]
                                    [ks * 32 + (lane >> 4) * 8];
#pragma unroll
      for (int ni = 0; ni < 4; ++ni)
        bfr[ni] = *(const bf16x8*)&Bl[wn * 64 + ni * 16 + (lane & 15)]
                                     [ks * 32 + (lane >> 4) * 8];
#pragma unroll
      for (int mi = 0; mi < 4; ++mi)
#pragma unroll
        for (int ni = 0; ni < 4; ++ni)
          acc[mi][ni] = __builtin_amdgcn_mfma_f32_16x16x32_bf16(
              af[mi], bfr[ni], acc[mi][ni], 0, 0, 0);
    }
    __syncthreads();
  }
  // fused stats (fp32, before bf16 rounding of outputs)
#pragma unroll
  for (int mi = 0; mi < 4; ++mi)
#pragma unroll
    for (int j = 0; j < 4; ++j) {
      float s  = acc[mi][0][j] + acc[mi][1][j] + acc[mi][2][j] + acc[mi][3][j];
      float s2 = acc[mi][0][j]*acc[mi][0][j] + acc[mi][1][j]*acc[mi][1][j] +
                 acc[mi][2][j]*acc[mi][2][j] + acc[mi][3][j]*acc[mi][3][j];
#pragma unroll
      for (int off = 1; off < 16; off <<= 1) {
        s  += __shfl_xor(s, off);
        s2 += __shfl_xor(s2, off);
      }
      if ((lane & 15) == 0) {
        int mg = m0 + wm * 64 + mi * 16 + (lane >> 4) * 4 + j;
        atomicAdd(&ssum[24 + mg], s);
        atomicAdd(&s2sum[24 + mg], s2);
      }
    }
  // write bf16 to valsbf[b][512][N]
#pragma unroll
  for (int mi = 0; mi < 4; ++mi) {
#pragma unroll
    for (int ni = 0; ni < 4; ++ni) {
      int m = m0 + wm * 64 + mi * 16 + (lane >> 4) * 4;
      int n = n0 + wn * 64 + ni * 16 + (lane & 15);
#pragma unroll
      for (int j = 0; j < 4; ++j)
        valsbf[((size_t)b * 512 + m + j) * N_ + n] = f2bf(acc[mi][ni][j]);
    }
  }
}

// ============================================================
// bnfin: finalize BN -> scale/shift per channel
// ============================================================
__global__ __launch_bounds__(256) void bnfin_kernel(const float* __restrict__ ssum,
                                                    const float* __restrict__ s2sum,
                                                    const float* __restrict__ kg,
                                                    const float* __restrict__ kb,
                                                    const float* __restrict__ vg,
                                                    const float* __restrict__ vb,
                                                    float* __restrict__ scale,
                                                    float* __restrict__ shift) {
  const int o = blockIdx.x * 256 + threadIdx.x;
  if (o >= OC_) return;
  const float inv = 1.0f / (B_ * N_);
  float mu  = ssum[o] * inv;
  float var = s2sum[o] * inv - mu * mu;
  float g, be;
  if (o < 24) { g = kg[o]; be = kb[o]; }
  else        { g = vg[o - 24]; be = vb[o - 24]; }
  float sc = g * rsqrtf(var + 1e-5f);
  scale[o] = sc;
  shift[o] = be - mu * sc;
}

// ============================================================
// passk: per-point keys -> {r0,r1,r2, cell} + keys mean/var
// ============================================================
__global__ __launch_bounds__(256) void passk_kernel(const float* __restrict__ kvk,
                                                    const float* __restrict__ orig,
                                                    const float* __restrict__ proj,
                                                    const float* __restrict__ scale,
                                                    const float* __restrict__ shift,
                                                    float4* __restrict__ cellr,
                                                    float* __restrict__ kacc) {
  const int p = blockIdx.x * 256 + threadIdx.x;
  const int bh = p >> 13, n = p & (N_ - 1);
  const int b = bh >> 3, h = bh & 7;
  const float* Kb = kvk + (size_t)b * 24 * N_;
  float pt[3];
#pragma unroll
  for (int k = 0; k < 3; ++k) {
    int ch = h * 3 + k;
    float kr = fmaf(Kb[(size_t)ch * N_ + n], scale[ch], shift[ch]);
    pt[k] = orig[((size_t)b * 3 + k) * N_ + n] + kr;
  }
  float ksum = 0.f, ksq = 0.f;
  int cell = 0;
  float rr[3];
#pragma unroll
  for (int d = 0; d < 3; ++d) {
    const float* pr = proj + (h * 3 + d) * 3;
    float key = pr[0] * pt[0] + pr[1] * pt[1] + pr[2] * pt[2];
    ksum += key; ksq += key * key;
    float lat = tanhf(key);
    float c = (lat + 1.0f) * 15.5f;
    float fl = floorf(c);
    fl = fminf(fmaxf(fl, 0.0f), 30.0f);
    rr[d] = c - fl;
    cell += (int)fl * ((d == 0) ? 1024 : (d == 1) ? 32 : 1);
  }
  cellr[p] = make_float4(rr[0], rr[1], rr[2], __int_as_float(cell));
#pragma unroll
  for (int off = 32; off; off >>= 1) {
    ksum += __shfl_down(ksum, off);
    ksq  += __shfl_down(ksq, off);
  }
  if ((threadIdx.x & 63) == 0) {
    atomicAdd(&kacc[0], ksum);
    atomicAdd(&kacc[1], ksq);
  }
}

// ============================================================
// sortk: per-bh counting sort of points by cell (R6 version).
// Output: sorted[bh][i] = {r0,r1,r2, bitcast(cell | n<<15)}
// ============================================================
__global__ __launch_bounds__(1024, 1) void sortk_kernel(const float4* __restrict__ cellr,
                                                        float4* __restrict__ sorted) {
  const int bh = blockIdx.x;
  __shared__ int hist[NC_];      // 128 KiB
  __shared__ int wsum[16];
  const int t = threadIdx.x;
  for (int i = t; i < NC_; i += 1024) hist[i] = 0;
  __syncthreads();
  const float4* cr = cellr + (size_t)bh * N_;
#pragma unroll
  for (int i = 0; i < 8; ++i) {
    int cell = __float_as_int(cr[t + i * 1024].w);
    atomicAdd(&hist[cell], 1);
  }
  __syncthreads();
  const int base = t * 32;
  int s = 0;
#pragma unroll
  for (int j = 0; j < 32; ++j) s += hist[base + ((j + t) & 31)];
  const int lane = t & 63, wv = t >> 6;
  int sc = s;
#pragma unroll
  for (int off = 1; off < 64; off <<= 1) {
    int x = __shfl_up(sc, off);
    if (lane >= off) sc += x;
  }
  if (lane == 63) wsum[wv] = sc;
  __syncthreads();
  if (t < 16) {
    int x = wsum[t];
    int sc2 = x;
#pragma unroll
    for (int off = 1; off < 16; off <<= 1) {
      int y = __shfl_up(sc2, off);
      if (t >= off) sc2 += y;
    }
    wsum[t] = sc2 - x;
  }
  __syncthreads();
  int run = sc - s + wsum[wv];
#pragma unroll
  for (int j = 0; j < 32; ++j) {
    int idx = base + ((j + t) & 31);
    int v = hist[idx];
    hist[idx] = run;
    run += v;
  }
  __syncthreads();
  float4* dst = sorted + (size_t)bh * N_;
#pragma unroll
  for (int i = 0; i < 8; ++i) {
    int n = t + i * 1024;
    float4 m = cr[n];
    int cell = __float_as_int(m.w);
    int pos = atomicAdd(&hist[cell], 1);
    m.w = __int_as_float(cell | (n << 15));
    dst[pos] = m;
  }
}

// ============================================================
// accum (R6 structure, 512x16): block = (bh, feat), full 32^3
// grid in 128 KiB LDS. Thread owns 16 consecutive sorted
// entries; register run-merge with Z-SLIDE: when next cell ==
// cur+1 the window slides, flushing only the completed left
// column (4 atomics instead of 8). Values gathered as bf16.
// Coalesced non-atomic z write + fused occ.
// ============================================================
__global__ __launch_bounds__(512, 1) void accum_kernel(const unsigned short* __restrict__ valsbf,
                                                       const float* __restrict__ scale,
                                                       const float* __restrict__ shift,
                                                       const float4* __restrict__ sorted,
                                                       float* __restrict__ zout,
                                                       unsigned int* __restrict__ occ) {
  const int blk = blockIdx.x;       // bh*64 + f
  const int f   = blk & 63;
  const int bh  = blk >> 6;
  const int b = bh >> 3, h = bh & 7;
  __shared__ float tile[NC_];       // 128 KiB
  const int t = threadIdx.x;
#pragma unroll
  for (int i = 0; i < 16; ++i)
    ((float4*)tile)[t + i * 512] = make_float4(0.f, 0.f, 0.f, 0.f);
  __syncthreads();

  const int ch = 24 + h * 64 + f;
  const float sc = scale[ch], sh = shift[ch];
  const unsigned short* kvrow = valsbf + ((size_t)b * 512 + h * 64 + f) * N_;
  const float4* sp = sorted + (size_t)bh * N_;
  const int base = t * 16;

  // prefetch 16 entries + 16 bf16 gathers (independent loads)
  float4 e[16];
#pragma unroll
  for (int i = 0; i < 16; ++i) e[i] = sp[base + i];
  unsigned short kvv[16];
#pragma unroll
  for (int i = 0; i < 16; ++i)
    kvv[i] = kvrow[((unsigned)__float_as_int(e[i].w)) >> 15];

#define FLUSH8()                                                    \
  {                                                                 \
    atomicAdd(&tile[cur],        m0_);                              \
    atomicAdd(&tile[cur + 1],    m1_);                              \
    atomicAdd(&tile[cur + 32],   m2_);                              \
    atomicAdd(&tile[cur + 33],   m3_);                              \
    atomicAdd(&tile[cur + 1024], m4_);                              \
    atomicAdd(&tile[cur + 1025], m5_);                              \
    atomicAdd(&tile[cur + 1056], m6_);                              \
    atomicAdd(&tile[cur + 1057], m7_);                              \
  }

  float m0_ = 0.f, m1_ = 0.f, m2_ = 0.f, m3_ = 0.f;
  float m4_ = 0.f, m5_ = 0.f, m6_ = 0.f, m7_ = 0.f;
  int cur = __float_as_int(e[0].w) & 32767;
#pragma unroll
  for (int i = 0; i < 16; ++i) {
    int cell = __float_as_int(e[i].w) & 32767;
    if (cell != cur) {
      if (cell == cur + 1) {
        // slide window by +1 in z: flush completed left column
        atomicAdd(&tile[cur],        m0_);
        atomicAdd(&tile[cur + 32],   m2_);
        atomicAdd(&tile[cur + 1024], m4_);
        atomicAdd(&tile[cur + 1056], m6_);
        m0_ = m1_; m2_ = m3_; m4_ = m5_; m6_ = m7_;
        m1_ = 0.f; m3_ = 0.f; m5_ = 0.f; m7_ = 0.f;
      } else {
        FLUSH8();
        m0_ = m1_ = m2_ = m3_ = m4_ = m5_ = m6_ = m7_ = 0.f;
      }
      cur = cell;
    }
    float v  = fmaf(bf2f(kvv[i]), sc, sh);
    float r0 = e[i].x, r1 = e[i].y, r2 = e[i].z;
    float va = v * (1.f - r0), vb = v * r0;
    float c00 = (1.f - r1) * (1.f - r2), c01 = (1.f - r1) * r2;
    float c10 = r1 * (1.f - r2),         c11 = r1 * r2;
    m0_ = fmaf(va, c00, m0_); m1_ = fmaf(va, c01, m1_);
    m2_ = fmaf(va, c10, m2_); m3_ = fmaf(va, c11, m3_);
    m4_ = fmaf(vb, c00, m4_); m5_ = fmaf(vb, c01, m5_);
    m6_ = fmaf(vb, c10, m6_); m7_ = fmaf(vb, c11, m7_);
  }
  FLUSH8();
#undef FLUSH8
  __syncthreads();

  unsigned int cnt = 0;
  float* dst = zout + (size_t)blk * NC_;
#pragma unroll
  for (int i = 0; i < 16; ++i) {
    float4 v = ((const float4*)tile)[t + i * 512];
    cnt += (fabsf(v.x) > 1e-9f) ? 1u : 0u;
    cnt += (fabsf(v.y) > 1e-9f) ? 1u : 0u;
    cnt += (fabsf(v.z) > 1e-9f) ? 1u : 0u;
    cnt += (fabsf(v.w) > 1e-9f) ? 1u : 0u;
    ((float4*)dst)[t + i * 512] = v;
  }
#pragma unroll
  for (int off = 32; off; off >>= 1) cnt += __shfl_down(cnt, off);
  __shared__ unsigned int wc[8];
  if ((t & 63) == 0) wc[t >> 6] = cnt;
  __syncthreads();
  if (t == 0) {
    unsigned int s = 0;
#pragma unroll
    for (int i = 0; i < 8; ++i) s += wc[i];
    atomicAdd(occ, s);
  }
}

// ============================================================
// fallback path (small ws): fp32 everything, direct splat
// ============================================================
__global__ __launch_bounds__(256) void gemm_full_kernel(const float* __restrict__ W,
                                                        const float* __restrict__ X,
                                                        float* __restrict__ KV) {
  const int n0 = blockIdx.x * 256;
  const int m0 = blockIdx.y * 64;
  const int b  = blockIdx.z;
  __shared__ float Wt[32][68];
  __shared__ float In[32][260];
  const int t  = threadIdx.x;
  const int tx = t & 31;
  const int ty = t >> 5;
  float acc[8][8];
#pragma unroll
  for (int r = 0; r < 8; ++r)
#pragma unroll
    for (int c = 0; c < 8; ++c) acc[r][c] = 0.f;
  const float* Xb = X + (size_t)b * MD_ * N_;
  for (int k0 = 0; k0 < MD_; k0 += 32) {
#pragma unroll
    for (int i = 0; i < 8; ++i) {
      int idx = t + i * 256;
      int m = idx >> 5, k = idx & 31;
      int mm = m0 + m;
      Wt[k][m] = (mm < OC_) ? W[(size_t)mm * MD_ + (k0 + k)] : 0.f;
    }
#pragma unroll
    for (int i = 0; i < 8; ++i) {
      int slot = t + i * 256;
      int k = slot >> 6, n4 = slot & 63;
      float4 v = *(const float4*)(Xb + (size_t)(k0 + k) * N_ + n0 + n4 * 4);
      *(float4*)&In[k][n4 * 4] = v;
    }
    __syncthreads();
#pragma unroll
    for (int k = 0; k < 32; ++k) {
      float a[8], bb[8];
      *(float4*)&a[0]  = *(const float4*)&Wt[k][ty * 8];
      *(float4*)&a[4]  = *(const float4*)&Wt[k][ty * 8 + 4];
      *(float4*)&bb[0] = *(const float4*)&In[k][tx * 4];
      *(float4*)&bb[4] = *(const float4*)&In[k][128 + tx * 4];
#pragma unroll
      for (int r = 0; r < 8; ++r)
#pragma unroll
        for (int c = 0; c < 8; ++c)
          acc[r][c] = fmaf(a[r], bb[c], acc[r][c]);
    }
    __syncthreads();
  }
#pragma unroll
  for (int r = 0; r < 8; ++r) {
    int mm = m0 + ty * 8 + r;
    if (mm < OC_) {
      float* dst = KV + ((size_t)b * OC_ + mm) * N_ + n0;
      *(float4*)(dst + tx * 4)       = *(float4*)&acc[r][0];
      *(float4*)(dst + 128 + tx * 4) = *(float4*)&acc[r][4];
    }
  }
}

__global__ __launch_bounds__(256) void bn_kernel(const float* __restrict__ KV,
                                                 const float* __restrict__ kg,
                                                 const float* __restrict__ kb,
                                                 const float* __restrict__ vg,
                                                 const float* __restrict__ vb,
                                                 float* __restrict__ scale,
                                                 float* __restrict__ shift) {
  const int o = blockIdx.x;
  const int t = threadIdx.x;
  float s = 0.f, s2 = 0.f;
  for (int idx = t; idx < B_ * N_; idx += 256) {
    int bb = idx >> 13, n = idx & (N_ - 1);
    float v = KV[((size_t)bb * OC_ + o) * N_ + n];
    s += v; s2 = fmaf(v, v, s2);
  }
#pragma unroll
  for (int off = 32; off; off >>= 1) {
    s  += __shfl_down(s, off);
    s2 += __shfl_down(s2, off);
  }
  __shared__ float rs[4], rs2[4];
  if ((t & 63) == 0) { rs[t >> 6] = s; rs2[t >> 6] = s2; }
  __syncthreads();
  if (t == 0) {
    s  = rs[0] + rs[1] + rs[2] + rs[3];
    s2 = rs2[0] + rs2[1] + rs2[2] + rs2[3];
    const float inv = 1.0f / (B_ * N_);
    float mu  = s * inv;
    float var = s2 * inv - mu * mu;
    float g, be;
    if (o < 24) { g = kg[o]; be = kb[o]; }
    else        { g = vg[o - 24]; be = vb[o - 24]; }
    float sc = g * rsqrtf(var + 1e-5f);
    scale[o] = sc;
    shift[o] = be - mu * sc;
  }
}

__global__ __launch_bounds__(256) void splat_final_kernel(const float* __restrict__ KV,
                                                          const float* __restrict__ orig,
                                                          const float* __restrict__ proj,
                                                          const float* __restrict__ scale,
                                                          const float* __restrict__ shift,
                                                          float* __restrict__ Z,
                                                          float* __restrict__ kacc) {
  const int bh = blockIdx.x >> 7;
  const int n0 = (blockIdx.x & 127) << 6;
  const int b = bh >> 3, h = bh & 7;
  __shared__ float vals[64][65];
  __shared__ int   cellS[64];
  __shared__ float rS[64][4];
  const int t = threadIdx.x;
  const float* KVb = KV + (size_t)b * OC_ * N_;
  const int ch0 = 24 + h * 64;
#pragma unroll
  for (int i = 0; i < 16; ++i) {
    int idx = t + i * 256;
    int f = idx >> 6, p = idx & 63;
    int ch = ch0 + f;
    vals[f][p] = fmaf(KVb[(size_t)ch * N_ + n0 + p], scale[ch], shift[ch]);
  }
  if (t < 64) {
    const int n = n0 + t;
    float pt[3];
#pragma unroll
    for (int k = 0; k < 3; ++k) {
      int ch = h * 3 + k;
      float kr = fmaf(KVb[(size_t)ch * N_ + n], scale[ch], shift[ch]);
      pt[k] = orig[((size_t)b * 3 + k) * N_ + n] + kr;
    }
    float ksum = 0.f, ksq = 0.f;
    int cell = 0;
    float rr[3];
#pragma unroll
    for (int d = 0; d < 3; ++d) {
      const float* pr = proj + (h * 3 + d) * 3;
      float key = pr[0] * pt[0] + pr[1] * pt[1] + pr[2] * pt[2];
      ksum += key; ksq += key * key;
      float lat = tanhf(key);
      float c = (lat + 1.0f) * 15.5f;
      float fl = floorf(c);
      fl = fminf(fmaxf(fl, 0.0f), 30.0f);
      rr[d] = c - fl;
      cell += (int)fl * ((d == 0) ? 1024 : (d == 1) ? 32 : 1);
    }
    cellS[t] = cell;
    rS[t][0] = rr[0]; rS[t][1] = rr[1]; rS[t][2] = rr[2];
#pragma unroll
    for (int off = 32; off; off >>= 1) {
      ksum += __shfl_down(ksum, off);
      ksq  += __shfl_down(ksq, off);
    }
    if (t == 0) { atomicAdd(&kacc[0], ksum); atomicAdd(&kacc[1], ksq); }
  }
  __syncthreads();
  const int w = t >> 6, l = t & 63;
  for (int pi = 0; pi < 16; ++pi) {
    int p = w * 16 + pi;
    int cell = cellS[p];
    float r0 = rS[p][0], r1 = rS[p][1], r2 = rS[p][2];
    float u0 = 1.f - r0, u1 = 1.f - r1, u2 = 1.f - r2;
    float v = vals[l][p];
#pragma unroll
    for (int c = 0; c < 8; ++c) {
      float wt = ((c & 4) ? r0 : u0) * ((c & 2) ? r1 : u1) * ((c & 1) ? r2 : u2);
      int cc = cell + ((c & 4) ? 1024 : 0) + ((c & 2) ? 32 : 0) + (c & 1);
      atomicAdd(Z + (size_t)(bh * 64 + l) * NC_ + cc, v * wt);
    }
  }
}

__global__ __launch_bounds__(256) void count_kernel(const float* __restrict__ Z,
                                                    unsigned int* __restrict__ occ) {
  unsigned int cnt = 0;
  for (long long i = (long long)blockIdx.x * blockDim.x + threadIdx.x; i < ZTOT_;
       i += (long long)gridDim.x * blockDim.x)
    cnt += (fabsf(Z[i]) > 1e-9f) ? 1u : 0u;
#pragma unroll
  for (int off = 32; off; off >>= 1) cnt += __shfl_down(cnt, off);
  __shared__ unsigned int wc[4];
  const int t = threadIdx.x;
  if ((t & 63) == 0) wc[t >> 6] = cnt;
  __syncthreads();
  if (t == 0) atomicAdd(occ, wc[0] + wc[1] + wc[2] + wc[3]);
}

__global__ void finalize_kernel(const unsigned int* __restrict__ occ,
                                const float* __restrict__ kacc,
                                float* __restrict__ tail) {
  float mean = kacc[0] / NKEYS_;
  tail[0] = (float)(*occ) * (1.0f / 2048.0f);
  tail[1] = mean;
  tail[2] = kacc[1] / NKEYS_ - mean * mean;
}

// ============================================================
extern "C" void kernel_launch(void* const* d_in, const int* in_sizes, int n_in,
                              void* d_out, int out_size, void* d_ws, size_t ws_size,
                              hipStream_t stream) {
  const float* X    = (const float*)d_in[0];
  const float* orig = (const float*)d_in[1];
  const float* W    = (const float*)d_in[2];
  const float* kg   = (const float*)d_in[3];
  const float* kb   = (const float*)d_in[4];
  const float* vg   = (const float*)d_in[5];
  const float* vb   = (const float*)d_in[6];
  const float* proj = (const float*)d_in[7];
  float* out = (float*)d_out;

  float* P = (float*)d_ws;
  float* ssum  = P;                         // [544]
  float* s2sum = P + 544;                   // [544]
  float* kacc  = P + 1088;                  // [2]
  unsigned int* occ = (unsigned int*)(P + 1090);
  float* scale = P + 1152;                  // [536]
  float* shift = P + 1696;                  // [536]
  char* wsb = (char*)d_ws;

  const size_t need = (size_t)60 << 20;
  if (ws_size >= need) {
    unsigned short* Wbf    = (unsigned short*)(wsb + 65536);        // 512 KB
    float*          kvk    = (float*)(wsb + ((size_t)1 << 20));     // 3 MB
    float4*         sorted = (float4*)(wsb + ((size_t)5 << 20));    // 4 MB
    unsigned short* valsbf = (unsigned short*)(wsb + ((size_t)9 << 20)); // 33.6 MB -> ends ~43MB
    // staging in d_out's z region (consumed before accum writes z)
    unsigned short* Xt = (unsigned short*)out;                      // 32 MB
    float4* cellr = (float4*)((char*)out + ((size_t)48 << 20));     // 4 MB

    hipMemsetAsync(P, 0, 4368, stream);

    convw_kernel<<<256, 256, 0, stream>>>(W, Wbf);
    convxt_kernel<<<dim3(128, 8, 4), 256, 0, stream>>>(X, Xt);
    gemm_keys<<<dim3(32, 4), 256, 0, stream>>>(W, X, kvk, ssum, s2sum);
    gemm_mfma<<<dim3(4, 64, 4), 256, 0, stream>>>(Wbf, Xt, valsbf, ssum, s2sum);
    bnfin_kernel<<<3, 256, 0, stream>>>(ssum, s2sum, kg, kb, vg, vb, scale, shift);
    passk_kernel<<<NPTS_ / 256, 256, 0, stream>>>(kvk, orig, proj, scale, shift,
                                                  cellr, kacc);
    sortk_kernel<<<32, 1024, 0, stream>>>(cellr, sorted);
    accum_kernel<<<2048, 512, 0, stream>>>(valsbf, scale, shift, sorted, out, occ);
    finalize_kernel<<<1, 1, 0, stream>>>(occ, kacc, out + ZTOT_);
  } else {
    float* kv = (float*)(wsb + 16384);
    hipMemsetAsync(P, 0, 4368, stream);
    hipMemsetAsync(out, 0, (size_t)ZTOT_ * 4, stream);
    gemm_full_kernel<<<dim3(N_ / 256, 9, B_), 256, 0, stream>>>(W, X, kv);
    bn_kernel<<<OC_, 256, 0, stream>>>(kv, kg, kb, vg, vb, scale, shift);
    splat_final_kernel<<<B_ * HEADS_ * (N_ / 64), 256, 0, stream>>>(
        kv, orig, proj, scale, shift, out, kacc);
    count_kernel<<<2048, 256, 0, stream>>>(out, occ);
    finalize_kernel<<<1, 1, 0, stream>>>(occ, kacc, out + ZTOT_);
  }
}

// Round 14
// 593.202 us; speedup vs baseline: 1.5223x; 1.0144x over previous
//
#include <hip/hip_runtime.h>

// ---- problem constants ----
#define B_     4
#define N_     8192
#define MD_    512
#define OC_    536        // HEADS*(FEAT+3)
#define HEADS_ 8
#define FEAT_  64
#define NC_    32768      // 32^3 cells
#define ZTOT_  67108864ll // B*HEADS*FEAT*NC
#define NPTS_  262144     // B*HEADS*N
#define NKEYS_ 786432.0f  // B*HEADS*3*N
#define BNINV_ (1.0f / 32768.0f)

typedef __bf16 bf16x8 __attribute__((ext_vector_type(8)));
typedef float  f32x4  __attribute__((ext_vector_type(4)));

__device__ __forceinline__ unsigned short f2bf(float f) {
  unsigned int u = __float_as_uint(f);
  u = (u + 0x7FFFu + ((u >> 16) & 1u)) >> 16;   // round-to-nearest-even
  return (unsigned short)u;
}
__device__ __forceinline__ float bf2f(unsigned short s) {
  return __uint_as_float(((unsigned)s) << 16);
}

// ============================================================
// convW: W rows 24..535 -> bf16 [512][512]
// ============================================================
__global__ __launch_bounds__(256) void convw_kernel(const float* __restrict__ W,
                                                    unsigned short* __restrict__ Wbf) {
  int i = (blockIdx.x * 256 + threadIdx.x) * 4;
  float4 v = *(const float4*)&W[24 * 512 + i];
  ushort4 o;
  o.x = f2bf(v.x); o.y = f2bf(v.y); o.z = f2bf(v.z); o.w = f2bf(v.w);
  *(ushort4*)&Wbf[i] = o;
}

// ============================================================
// convXt: X[b][k][n] f32 -> Xt[b][n][k] bf16 (transposed)
// ============================================================
__global__ __launch_bounds__(256) void convxt_kernel(const float* __restrict__ X,
                                                     unsigned short* __restrict__ Xt) {
  const int n0 = blockIdx.x * 64;
  const int k0 = blockIdx.y * 64;
  const int b  = blockIdx.z;
  __shared__ float T[64][65];
  const int t = threadIdx.x;
#pragma unroll
  for (int i = 0; i < 16; ++i) {
    int idx = t + i * 256;
    int kk = idx >> 6, nn = idx & 63;
    T[kk][nn] = X[((size_t)b * MD_ + k0 + kk) * N_ + n0 + nn];
  }
  __syncthreads();
  const int sub = t & 7;
  const int nb  = t >> 3;
#pragma unroll
  for (int i = 0; i < 2; ++i) {
    int nn = nb + i * 32;
    ushort4 o0, o1;
    o0.x = f2bf(T[sub * 8 + 0][nn]); o0.y = f2bf(T[sub * 8 + 1][nn]);
    o0.z = f2bf(T[sub * 8 + 2][nn]); o0.w = f2bf(T[sub * 8 + 3][nn]);
    o1.x = f2bf(T[sub * 8 + 4][nn]); o1.y = f2bf(T[sub * 8 + 5][nn]);
    o1.z = f2bf(T[sub * 8 + 6][nn]); o1.w = f2bf(T[sub * 8 + 7][nn]);
    unsigned short* dst = Xt + ((size_t)b * N_ + n0 + nn) * MD_ + k0 + sub * 8;
    *(ushort4*)dst = o0;
    *(ushort4*)(dst + 4) = o1;
  }
}

// ============================================================
// gemm_keys: fp32-exact GEMM for key channels -> kvk[b][24][N]
// + fused per-channel stats
// ============================================================
__global__ __launch_bounds__(256) void gemm_keys(const float* __restrict__ W,
                                                 const float* __restrict__ X,
                                                 float* __restrict__ kvk,
                                                 float* __restrict__ ssum,
                                                 float* __restrict__ s2sum) {
  const int n0 = blockIdx.x * 256;
  const int b  = blockIdx.y;
  __shared__ float Wt[32][26];
  __shared__ float In[32][260];
  const int t  = threadIdx.x;
  const int cg = t & 63;
  const int rb = (t >> 6) * 6;
  float acc[6][4];
#pragma unroll
  for (int r = 0; r < 6; ++r)
#pragma unroll
    for (int c = 0; c < 4; ++c) acc[r][c] = 0.f;
  const float* Xb = X + (size_t)b * MD_ * N_;
  for (int k0 = 0; k0 < MD_; k0 += 32) {
#pragma unroll
    for (int i = 0; i < 3; ++i) {
      int idx = t * 3 + i;
      int m = idx % 24, k = idx / 24;
      Wt[k][m] = W[(size_t)m * MD_ + k0 + k];
    }
#pragma unroll
    for (int i = 0; i < 8; ++i) {
      int slot = t + i * 256;
      int k = slot >> 6, n4 = slot & 63;
      float4 v = *(const float4*)(Xb + (size_t)(k0 + k) * N_ + n0 + n4 * 4);
      *(float4*)&In[k][n4 * 4] = v;
    }
    __syncthreads();
#pragma unroll
    for (int k = 0; k < 32; ++k) {
      float4 bv = *(const float4*)&In[k][cg * 4];
#pragma unroll
      for (int r = 0; r < 6; ++r) {
        float a = Wt[k][rb + r];
        acc[r][0] = fmaf(a, bv.x, acc[r][0]);
        acc[r][1] = fmaf(a, bv.y, acc[r][1]);
        acc[r][2] = fmaf(a, bv.z, acc[r][2]);
        acc[r][3] = fmaf(a, bv.w, acc[r][3]);
      }
    }
    __syncthreads();
  }
#pragma unroll
  for (int r = 0; r < 6; ++r) {
    float* dst = kvk + ((size_t)b * 24 + rb + r) * N_ + n0 + cg * 4;
    *(float4*)dst = *(float4*)&acc[r][0];
    float s = acc[r][0] + acc[r][1] + acc[r][2] + acc[r][3];
    float s2 = acc[r][0]*acc[r][0] + acc[r][1]*acc[r][1] +
               acc[r][2]*acc[r][2] + acc[r][3]*acc[r][3];
#pragma unroll
    for (int off = 32; off; off >>= 1) {
      s  += __shfl_down(s, off);
      s2 += __shfl_down(s2, off);
    }
    if (cg == 0) { atomicAdd(&ssum[rb + r], s); atomicAdd(&s2sum[rb + r], s2); }
  }
}

// ============================================================
// gemm_mfma: bf16 MFMA GEMM for value channels -> valsbf
// [b][512][N] bf16 (un-BN'd) + fused fp32 per-channel stats.
// grid (n=64, m=4, b). Epilogue staged through LDS for
// coalesced 128B-per-row stores (8 dwordx4 stores/thread).
// ============================================================
__global__ __launch_bounds__(256) void gemm_mfma(const unsigned short* __restrict__ Wbf,
                                                 const unsigned short* __restrict__ Xt,
                                                 unsigned short* __restrict__ valsbf,
                                                 float* __restrict__ ssum,
                                                 float* __restrict__ s2sum) {
  const int n0 = blockIdx.x * 128;
  const int m0 = blockIdx.y * 128;
  const int b  = blockIdx.z;
  __shared__ __align__(16) unsigned short smem[128 * 144];  // 36 KB
#define AL(r, c) smem[(r) * 72 + (c)]
#define BL(r, c) smem[128 * 72 + (r) * 72 + (c)]
#define CS(r, c) smem[(r) * 136 + (c)]
  const int t = threadIdx.x;
  const int lane = t & 63, wave = t >> 6;
  const int wm = wave >> 1, wn = wave & 1;
  f32x4 acc[4][4];
#pragma unroll
  for (int mi = 0; mi < 4; ++mi)
#pragma unroll
    for (int ni = 0; ni < 4; ++ni)
#pragma unroll
      for (int j = 0; j < 4; ++j) acc[mi][ni][j] = 0.f;

  const unsigned short* Xb = Xt + ((size_t)b * N_ + n0) * MD_;
  for (int k0 = 0; k0 < MD_; k0 += 64) {
#pragma unroll
    for (int i = 0; i < 4; ++i) {
      int chunk = t + i * 256;
      int r = chunk >> 3, c = chunk & 7;
      *(uint4*)&AL(r, c * 8) =
          *(const uint4*)&Wbf[(size_t)(m0 + r) * MD_ + k0 + c * 8];
    }
#pragma unroll
    for (int i = 0; i < 4; ++i) {
      int chunk = t + i * 256;
      int r = chunk >> 3, c = chunk & 7;
      *(uint4*)&BL(r, c * 8) =
          *(const uint4*)&Xb[(size_t)r * MD_ + k0 + c * 8];
    }
    __syncthreads();
#pragma unroll
    for (int ks = 0; ks < 2; ++ks) {
      bf16x8 af[4], bfr[4];
#pragma unroll
      for (int mi = 0; mi < 4; ++mi)
        af[mi] = *(const bf16x8*)&AL(wm * 64 + mi * 16 + (lane & 15),
                                     ks * 32 + (lane >> 4) * 8);
#pragma unroll
      for (int ni = 0; ni < 4; ++ni)
        bfr[ni] = *(const bf16x8*)&BL(wn * 64 + ni * 16 + (lane & 15),
                                      ks * 32 + (lane >> 4) * 8);
#pragma unroll
      for (int mi = 0; mi < 4; ++mi)
#pragma unroll
        for (int ni = 0; ni < 4; ++ni)
          acc[mi][ni] = __builtin_amdgcn_mfma_f32_16x16x32_bf16(
              af[mi], bfr[ni], acc[mi][ni], 0, 0, 0);
    }
    __syncthreads();
  }
  // fused stats (fp32, before bf16 rounding)
#pragma unroll
  for (int mi = 0; mi < 4; ++mi)
#pragma unroll
    for (int j = 0; j < 4; ++j) {
      float s  = acc[mi][0][j] + acc[mi][1][j] + acc[mi][2][j] + acc[mi][3][j];
      float s2 = acc[mi][0][j]*acc[mi][0][j] + acc[mi][1][j]*acc[mi][1][j] +
                 acc[mi][2][j]*acc[mi][2][j] + acc[mi][3][j]*acc[mi][3][j];
#pragma unroll
      for (int off = 1; off < 16; off <<= 1) {
        s  += __shfl_xor(s, off);
        s2 += __shfl_xor(s2, off);
      }
      if ((lane & 15) == 0) {
        int mg = m0 + wm * 64 + mi * 16 + (lane >> 4) * 4 + j;
        atomicAdd(&ssum[24 + mg], s);
        atomicAdd(&s2sum[24 + mg], s2);
      }
    }
  // stage bf16 C-tile in LDS (overwrites A/B staging; safe after last barrier)
#pragma unroll
  for (int mi = 0; mi < 4; ++mi)
#pragma unroll
    for (int ni = 0; ni < 4; ++ni) {
      int row = wm * 64 + mi * 16 + (lane >> 4) * 4;
      int col = wn * 64 + ni * 16 + (lane & 15);
#pragma unroll
      for (int j = 0; j < 4; ++j)
        CS(row + j, col) = f2bf(acc[mi][ni][j]);
    }
  __syncthreads();
  // coalesced writeback: 8 lanes per 128B row segment
#pragma unroll
  for (int i = 0; i < 4; ++i) {
    int row = (t >> 3) + i * 32;
    int cb  = (t & 7) * 16;
    uint4 lo = *(const uint4*)&CS(row, cb);
    uint4 hi = *(const uint4*)&CS(row, cb + 8);
    unsigned short* dst = valsbf + ((size_t)b * 512 + m0 + row) * N_ + n0 + cb;
    *(uint4*)dst       = lo;
    *(uint4*)(dst + 8) = hi;
  }
#undef AL
#undef BL
#undef CS
}

// ============================================================
// passk: per-point keys (BN finalize inlined) -> {r0,r1,r2,cell}
// + keys mean/var partials
// ============================================================
__global__ __launch_bounds__(256) void passk_kernel(const float* __restrict__ kvk,
                                                    const float* __restrict__ orig,
                                                    const float* __restrict__ proj,
                                                    const float* __restrict__ ssum,
                                                    const float* __restrict__ s2sum,
                                                    const float* __restrict__ kg,
                                                    const float* __restrict__ kb,
                                                    float4* __restrict__ cellr,
                                                    float* __restrict__ kacc) {
  const int p = blockIdx.x * 256 + threadIdx.x;
  const int bh = p >> 13, n = p & (N_ - 1);
  const int b = bh >> 3, h = bh & 7;
  const float* Kb = kvk + (size_t)b * 24 * N_;
  float pt[3];
#pragma unroll
  for (int k = 0; k < 3; ++k) {
    int ch = h * 3 + k;
    float mu  = ssum[ch] * BNINV_;
    float var = s2sum[ch] * BNINV_ - mu * mu;
    float sck = kg[ch] * rsqrtf(var + 1e-5f);
    float shk = kb[ch] - mu * sck;
    float kr = fmaf(Kb[(size_t)ch * N_ + n], sck, shk);
    pt[k] = orig[((size_t)b * 3 + k) * N_ + n] + kr;
  }
  float ksum = 0.f, ksq = 0.f;
  int cell = 0;
  float rr[3];
#pragma unroll
  for (int d = 0; d < 3; ++d) {
    const float* pr = proj + (h * 3 + d) * 3;
    float key = pr[0] * pt[0] + pr[1] * pt[1] + pr[2] * pt[2];
    ksum += key; ksq += key * key;
    float lat = tanhf(key);
    float c = (lat + 1.0f) * 15.5f;
    float fl = floorf(c);
    fl = fminf(fmaxf(fl, 0.0f), 30.0f);
    rr[d] = c - fl;
    cell += (int)fl * ((d == 0) ? 1024 : (d == 1) ? 32 : 1);
  }
  cellr[p] = make_float4(rr[0], rr[1], rr[2], __int_as_float(cell));
#pragma unroll
  for (int off = 32; off; off >>= 1) {
    ksum += __shfl_down(ksum, off);
    ksq  += __shfl_down(ksq, off);
  }
  if ((threadIdx.x & 63) == 0) {
    atomicAdd(&kacc[0], ksum);
    atomicAdd(&kacc[1], ksq);
  }
}

// ============================================================
// sortk: per-bh counting sort of points by cell.
// Output: sorted[bh][i] = {r0,r1,r2, bitcast(cell | n<<15)}
// ============================================================
__global__ __launch_bounds__(1024, 1) void sortk_kernel(const float4* __restrict__ cellr,
                                                        float4* __restrict__ sorted) {
  const int bh = blockIdx.x;
  __shared__ int hist[NC_];      // 128 KiB
  __shared__ int wsum[16];
  const int t = threadIdx.x;
  for (int i = t; i < NC_; i += 1024) hist[i] = 0;
  __syncthreads();
  const float4* cr = cellr + (size_t)bh * N_;
#pragma unroll
  for (int i = 0; i < 8; ++i) {
    int cell = __float_as_int(cr[t + i * 1024].w);
    atomicAdd(&hist[cell], 1);
  }
  __syncthreads();
  const int base = t * 32;
  int s = 0;
#pragma unroll
  for (int j = 0; j < 32; ++j) s += hist[base + ((j + t) & 31)];
  const int lane = t & 63, wv = t >> 6;
  int sc = s;
#pragma unroll
  for (int off = 1; off < 64; off <<= 1) {
    int x = __shfl_up(sc, off);
    if (lane >= off) sc += x;
  }
  if (lane == 63) wsum[wv] = sc;
  __syncthreads();
  if (t < 16) {
    int x = wsum[t];
    int sc2 = x;
#pragma unroll
    for (int off = 1; off < 16; off <<= 1) {
      int y = __shfl_up(sc2, off);
      if (t >= off) sc2 += y;
    }
    wsum[t] = sc2 - x;
  }
  __syncthreads();
  int run = sc - s + wsum[wv];
#pragma unroll
  for (int j = 0; j < 32; ++j) {
    int idx = base + ((j + t) & 31);
    int v = hist[idx];
    hist[idx] = run;
    run += v;
  }
  __syncthreads();
  float4* dst = sorted + (size_t)bh * N_;
#pragma unroll
  for (int i = 0; i < 8; ++i) {
    int n = t + i * 1024;
    float4 m = cr[n];
    int cell = __float_as_int(m.w);
    int pos = atomicAdd(&hist[cell], 1);
    m.w = __int_as_float(cell | (n << 15));
    dst[pos] = m;
  }
}

// ============================================================
// accum (R13-exact structure): block = (bh, feat), full 32^3
// grid in 128 KiB LDS. Thread owns 16 consecutive sorted
// entries; register run-merge with Z-SLIDE. BN finalize inlined.
// Values gathered as bf16. Coalesced non-atomic z write + occ.
// ============================================================
__global__ __launch_bounds__(512, 1) void accum_kernel(const unsigned short* __restrict__ valsbf,
                                                       const float* __restrict__ ssum,
                                                       const float* __restrict__ s2sum,
                                                       const float* __restrict__ vg,
                                                       const float* __restrict__ vb,
                                                       const float4* __restrict__ sorted,
                                                       float* __restrict__ zout,
                                                       unsigned int* __restrict__ occ) {
  const int blk = blockIdx.x;       // bh*64 + f
  const int f   = blk & 63;
  const int bh  = blk >> 6;
  const int b = bh >> 3, h = bh & 7;
  __shared__ float tile[NC_];       // 128 KiB
  const int t = threadIdx.x;
#pragma unroll
  for (int i = 0; i < 16; ++i)
    ((float4*)tile)[t + i * 512] = make_float4(0.f, 0.f, 0.f, 0.f);
  __syncthreads();

  const int ch = 24 + h * 64 + f;
  const float mu  = ssum[ch] * BNINV_;
  const float var = s2sum[ch] * BNINV_ - mu * mu;
  const float sc  = vg[ch - 24] * rsqrtf(var + 1e-5f);
  const float sh  = vb[ch - 24] - mu * sc;
  const unsigned short* kvrow = valsbf + ((size_t)b * 512 + h * 64 + f) * N_;
  const float4* sp = sorted + (size_t)bh * N_;
  const int base = t * 16;

  float4 e[16];
#pragma unroll
  for (int i = 0; i < 16; ++i) e[i] = sp[base + i];
  unsigned short kvv[16];
#pragma unroll
  for (int i = 0; i < 16; ++i)
    kvv[i] = kvrow[((unsigned)__float_as_int(e[i].w)) >> 15];

#define FLUSH8()                                                    \
  {                                                                 \
    atomicAdd(&tile[cur],        m0_);                              \
    atomicAdd(&tile[cur + 1],    m1_);                              \
    atomicAdd(&tile[cur + 32],   m2_);                              \
    atomicAdd(&tile[cur + 33],   m3_);                              \
    atomicAdd(&tile[cur + 1024], m4_);                              \
    atomicAdd(&tile[cur + 1025], m5_);                              \
    atomicAdd(&tile[cur + 1056], m6_);                              \
    atomicAdd(&tile[cur + 1057], m7_);                              \
  }

  float m0_ = 0.f, m1_ = 0.f, m2_ = 0.f, m3_ = 0.f;
  float m4_ = 0.f, m5_ = 0.f, m6_ = 0.f, m7_ = 0.f;
  int cur = __float_as_int(e[0].w) & 32767;
#pragma unroll
  for (int i = 0; i < 16; ++i) {
    int cell = __float_as_int(e[i].w) & 32767;
    if (cell != cur) {
      if (cell == cur + 1) {
        atomicAdd(&tile[cur],        m0_);
        atomicAdd(&tile[cur + 32],   m2_);
        atomicAdd(&tile[cur + 1024], m4_);
        atomicAdd(&tile[cur + 1056], m6_);
        m0_ = m1_; m2_ = m3_; m4_ = m5_; m6_ = m7_;
        m1_ = 0.f; m3_ = 0.f; m5_ = 0.f; m7_ = 0.f;
      } else {
        FLUSH8();
        m0_ = m1_ = m2_ = m3_ = m4_ = m5_ = m6_ = m7_ = 0.f;
      }
      cur = cell;
    }
    float v  = fmaf(bf2f(kvv[i]), sc, sh);
    float r0 = e[i].x, r1 = e[i].y, r2 = e[i].z;
    float va = v * (1.f - r0), vb2 = v * r0;
    float c00 = (1.f - r1) * (1.f - r2), c01 = (1.f - r1) * r2;
    float c10 = r1 * (1.f - r2),         c11 = r1 * r2;
    m0_ = fmaf(va, c00, m0_); m1_ = fmaf(va, c01, m1_);
    m2_ = fmaf(va, c10, m2_); m3_ = fmaf(va, c11, m3_);
    m4_ = fmaf(vb2, c00, m4_); m5_ = fmaf(vb2, c01, m5_);
    m6_ = fmaf(vb2, c10, m6_); m7_ = fmaf(vb2, c11, m7_);
  }
  FLUSH8();
#undef FLUSH8
  __syncthreads();

  unsigned int cnt = 0;
  float* dst = zout + (size_t)blk * NC_;
#pragma unroll
  for (int i = 0; i < 16; ++i) {
    float4 v = ((const float4*)tile)[t + i * 512];
    cnt += (fabsf(v.x) > 1e-9f) ? 1u : 0u;
    cnt += (fabsf(v.y) > 1e-9f) ? 1u : 0u;
    cnt += (fabsf(v.z) > 1e-9f) ? 1u : 0u;
    cnt += (fabsf(v.w) > 1e-9f) ? 1u : 0u;
    ((float4*)dst)[t + i * 512] = v;
  }
#pragma unroll
  for (int off = 32; off; off >>= 1) cnt += __shfl_down(cnt, off);
  __shared__ unsigned int wc[8];
  if ((t & 63) == 0) wc[t >> 6] = cnt;
  __syncthreads();
  if (t == 0) {
    unsigned int s = 0;
#pragma unroll
    for (int i = 0; i < 8; ++i) s += wc[i];
    atomicAdd(occ, s);
  }
}

// ============================================================
// fallback path (small ws): fp32 everything, direct splat
// ============================================================
__global__ __launch_bounds__(256) void gemm_full_kernel(const float* __restrict__ W,
                                                        const float* __restrict__ X,
                                                        float* __restrict__ KV) {
  const int n0 = blockIdx.x * 256;
  const int m0 = blockIdx.y * 64;
  const int b  = blockIdx.z;
  __shared__ float Wt[32][68];
  __shared__ float In[32][260];
  const int t  = threadIdx.x;
  const int tx = t & 31;
  const int ty = t >> 5;
  float acc[8][8];
#pragma unroll
  for (int r = 0; r < 8; ++r)
#pragma unroll
    for (int c = 0; c < 8; ++c) acc[r][c] = 0.f;
  const float* Xb = X + (size_t)b * MD_ * N_;
  for (int k0 = 0; k0 < MD_; k0 += 32) {
#pragma unroll
    for (int i = 0; i < 8; ++i) {
      int idx = t + i * 256;
      int m = idx >> 5, k = idx & 31;
      int mm = m0 + m;
      Wt[k][m] = (mm < OC_) ? W[(size_t)mm * MD_ + (k0 + k)] : 0.f;
    }
#pragma unroll
    for (int i = 0; i < 8; ++i) {
      int slot = t + i * 256;
      int k = slot >> 6, n4 = slot & 63;
      float4 v = *(const float4*)(Xb + (size_t)(k0 + k) * N_ + n0 + n4 * 4);
      *(float4*)&In[k][n4 * 4] = v;
    }
    __syncthreads();
#pragma unroll
    for (int k = 0; k < 32; ++k) {
      float a[8], bb[8];
      *(float4*)&a[0]  = *(const float4*)&Wt[k][ty * 8];
      *(float4*)&a[4]  = *(const float4*)&Wt[k][ty * 8 + 4];
      *(float4*)&bb[0] = *(const float4*)&In[k][tx * 4];
      *(float4*)&bb[4] = *(const float4*)&In[k][128 + tx * 4];
#pragma unroll
      for (int r = 0; r < 8; ++r)
#pragma unroll
        for (int c = 0; c < 8; ++c)
          acc[r][c] = fmaf(a[r], bb[c], acc[r][c]);
    }
    __syncthreads();
  }
#pragma unroll
  for (int r = 0; r < 8; ++r) {
    int mm = m0 + ty * 8 + r;
    if (mm < OC_) {
      float* dst = KV + ((size_t)b * OC_ + mm) * N_ + n0;
      *(float4*)(dst + tx * 4)       = *(float4*)&acc[r][0];
      *(float4*)(dst + 128 + tx * 4) = *(float4*)&acc[r][4];
    }
  }
}

__global__ __launch_bounds__(256) void bn_kernel(const float* __restrict__ KV,
                                                 const float* __restrict__ kg,
                                                 const float* __restrict__ kb,
                                                 const float* __restrict__ vg,
                                                 const float* __restrict__ vb,
                                                 float* __restrict__ scale,
                                                 float* __restrict__ shift) {
  const int o = blockIdx.x;
  const int t = threadIdx.x;
  float s = 0.f, s2 = 0.f;
  for (int idx = t; idx < B_ * N_; idx += 256) {
    int bb = idx >> 13, n = idx & (N_ - 1);
    float v = KV[((size_t)bb * OC_ + o) * N_ + n];
    s += v; s2 = fmaf(v, v, s2);
  }
#pragma unroll
  for (int off = 32; off; off >>= 1) {
    s  += __shfl_down(s, off);
    s2 += __shfl_down(s2, off);
  }
  __shared__ float rs[4], rs2[4];
  if ((t & 63) == 0) { rs[t >> 6] = s; rs2[t >> 6] = s2; }
  __syncthreads();
  if (t == 0) {
    s  = rs[0] + rs[1] + rs[2] + rs[3];
    s2 = rs2[0] + rs2[1] + rs2[2] + rs2[3];
    const float inv = 1.0f / (B_ * N_);
    float mu  = s * inv;
    float var = s2 * inv - mu * mu;
    float g, be;
    if (o < 24) { g = kg[o]; be = kb[o]; }
    else        { g = vg[o - 24]; be = vb[o - 24]; }
    float sc = g * rsqrtf(var + 1e-5f);
    scale[o] = sc;
    shift[o] = be - mu * sc;
  }
}

__global__ __launch_bounds__(256) void splat_final_kernel(const float* __restrict__ KV,
                                                          const float* __restrict__ orig,
                                                          const float* __restrict__ proj,
                                                          const float* __restrict__ scale,
                                                          const float* __restrict__ shift,
                                                          float* __restrict__ Z,
                                                          float* __restrict__ kacc) {
  const int bh = blockIdx.x >> 7;
  const int n0 = (blockIdx.x & 127) << 6;
  const int b = bh >> 3, h = bh & 7;
  __shared__ float vals[64][65];
  __shared__ int   cellS[64];
  __shared__ float rS[64][4];
  const int t = threadIdx.x;
  const float* KVb = KV + (size_t)b * OC_ * N_;
  const int ch0 = 24 + h * 64;
#pragma unroll
  for (int i = 0; i < 16; ++i) {
    int idx = t + i * 256;
    int f = idx >> 6, p = idx & 63;
    int ch = ch0 + f;
    vals[f][p] = fmaf(KVb[(size_t)ch * N_ + n0 + p], scale[ch], shift[ch]);
  }
  if (t < 64) {
    const int n = n0 + t;
    float pt[3];
#pragma unroll
    for (int k = 0; k < 3; ++k) {
      int ch = h * 3 + k;
      float kr = fmaf(KVb[(size_t)ch * N_ + n], scale[ch], shift[ch]);
      pt[k] = orig[((size_t)b * 3 + k) * N_ + n] + kr;
    }
    float ksum = 0.f, ksq = 0.f;
    int cell = 0;
    float rr[3];
#pragma unroll
    for (int d = 0; d < 3; ++d) {
      const float* pr = proj + (h * 3 + d) * 3;
      float key = pr[0] * pt[0] + pr[1] * pt[1] + pr[2] * pt[2];
      ksum += key; ksq += key * key;
      float lat = tanhf(key);
      float c = (lat + 1.0f) * 15.5f;
      float fl = floorf(c);
      fl = fminf(fmaxf(fl, 0.0f), 30.0f);
      rr[d] = c - fl;
      cell += (int)fl * ((d == 0) ? 1024 : (d == 1) ? 32 : 1);
    }
    cellS[t] = cell;
    rS[t][0] = rr[0]; rS[t][1] = rr[1]; rS[t][2] = rr[2];
#pragma unroll
    for (int off = 32; off; off >>= 1) {
      ksum += __shfl_down(ksum, off);
      ksq  += __shfl_down(ksq, off);
    }
    if (t == 0) { atomicAdd(&kacc[0], ksum); atomicAdd(&kacc[1], ksq); }
  }
  __syncthreads();
  const int w = t >> 6, l = t & 63;
  for (int pi = 0; pi < 16; ++pi) {
    int p = w * 16 + pi;
    int cell = cellS[p];
    float r0 = rS[p][0], r1 = rS[p][1], r2 = rS[p][2];
    float u0 = 1.f - r0, u1 = 1.f - r1, u2 = 1.f - r2;
    float v = vals[l][p];
#pragma unroll
    for (int c = 0; c < 8; ++c) {
      float wt = ((c & 4) ? r0 : u0) * ((c & 2) ? r1 : u1) * ((c & 1) ? r2 : u2);
      int cc = cell + ((c & 4) ? 1024 : 0) + ((c & 2) ? 32 : 0) + (c & 1);
      atomicAdd(Z + (size_t)(bh * 64 + l) * NC_ + cc, v * wt);
    }
  }
}

__global__ __launch_bounds__(256) void count_kernel(const float* __restrict__ Z,
                                                    unsigned int* __restrict__ occ) {
  unsigned int cnt = 0;
  for (long long i = (long long)blockIdx.x * blockDim.x + threadIdx.x; i < ZTOT_;
       i += (long long)gridDim.x * blockDim.x)
    cnt += (fabsf(Z[i]) > 1e-9f) ? 1u : 0u;
#pragma unroll
  for (int off = 32; off; off >>= 1) cnt += __shfl_down(cnt, off);
  __shared__ unsigned int wc[4];
  const int t = threadIdx.x;
  if ((t & 63) == 0) wc[t >> 6] = cnt;
  __syncthreads();
  if (t == 0) atomicAdd(occ, wc[0] + wc[1] + wc[2] + wc[3]);
}

__global__ void finalize_kernel(const unsigned int* __restrict__ occ,
                                const float* __restrict__ kacc,
                                float* __restrict__ tail) {
  float mean = kacc[0] / NKEYS_;
  tail[0] = (float)(*occ) * (1.0f / 2048.0f);
  tail[1] = mean;
  tail[2] = kacc[1] / NKEYS_ - mean * mean;
}

// ============================================================
extern "C" void kernel_launch(void* const* d_in, const int* in_sizes, int n_in,
                              void* d_out, int out_size, void* d_ws, size_t ws_size,
                              hipStream_t stream) {
  const float* X    = (const float*)d_in[0];
  const float* orig = (const float*)d_in[1];
  const float* W    = (const float*)d_in[2];
  const float* kg   = (const float*)d_in[3];
  const float* kb   = (const float*)d_in[4];
  const float* vg   = (const float*)d_in[5];
  const float* vb   = (const float*)d_in[6];
  const float* proj = (const float*)d_in[7];
  float* out = (float*)d_out;

  float* P = (float*)d_ws;
  float* ssum  = P;                         // [544]
  float* s2sum = P + 544;                   // [544]
  float* kacc  = P + 1088;                  // [2]
  unsigned int* occ = (unsigned int*)(P + 1090);
  float* scale = P + 1152;                  // [536] (fallback only)
  float* shift = P + 1696;                  // [536] (fallback only)
  char* wsb = (char*)d_ws;

  const size_t need = (size_t)60 << 20;
  if (ws_size >= need) {
    unsigned short* Wbf    = (unsigned short*)(wsb + 65536);        // 512 KB
    float*          kvk    = (float*)(wsb + ((size_t)1 << 20));     // 3 MB
    float4*         sorted = (float4*)(wsb + ((size_t)5 << 20));    // 4 MB
    unsigned short* valsbf = (unsigned short*)(wsb + ((size_t)9 << 20)); // 33.6 MB
    // staging in d_out's z region (consumed before accum writes z)
    unsigned short* Xt = (unsigned short*)out;                      // 32 MB
    float4* cellr = (float4*)((char*)out + ((size_t)48 << 20));     // 4 MB

    hipMemsetAsync(P, 0, 4368, stream);

    convw_kernel<<<256, 256, 0, stream>>>(W, Wbf);
    convxt_kernel<<<dim3(128, 8, 4), 256, 0, stream>>>(X, Xt);
    gemm_keys<<<dim3(32, 4), 256, 0, stream>>>(W, X, kvk, ssum, s2sum);
    gemm_mfma<<<dim3(64, 4, 4), 256, 0, stream>>>(Wbf, Xt, valsbf, ssum, s2sum);
    passk_kernel<<<NPTS_ / 256, 256, 0, stream>>>(kvk, orig, proj, ssum, s2sum,
                                                  kg, kb, cellr, kacc);
    sortk_kernel<<<32, 1024, 0, stream>>>(cellr, sorted);
    accum_kernel<<<2048, 512, 0, stream>>>(valsbf, ssum, s2sum, vg, vb,
                                           sorted, out, occ);
    finalize_kernel<<<1, 1, 0, stream>>>(occ, kacc, out + ZTOT_);
  } else {
    float* kv = (float*)(wsb + 16384);
    hipMemsetAsync(P, 0, 4368, stream);
    hipMemsetAsync(out, 0, (size_t)ZTOT_ * 4, stream);
    gemm_full_kernel<<<dim3(N_ / 256, 9, B_), 256, 0, stream>>>(W, X, kv);
    bn_kernel<<<OC_, 256, 0, stream>>>(kv, kg, kb, vg, vb, scale, shift);
    splat_final_kernel<<<B_ * HEADS_ * (N_ / 64), 256, 0, stream>>>(
        kv, orig, proj, scale, shift, out, kacc);
    count_kernel<<<2048, 256, 0, stream>>>(out, occ);
    finalize_kernel<<<1, 1, 0, stream>>>(occ, kacc, out + ZTOT_);
  }
}

// Round 15
// 483.909 us; speedup vs baseline: 1.8661x; 1.2259x over previous
//
#include <hip/hip_runtime.h>

// ---- problem constants ----
#define B_     4
#define N_     8192
#define MD_    512
#define OC_    536        // HEADS*(FEAT+3)
#define HEADS_ 8
#define FEAT_  64
#define NC_    32768      // 32^3 cells
#define ZTOT_  67108864ll // B*HEADS*FEAT*NC
#define NPTS_  262144     // B*HEADS*N
#define NKEYS_ 786432.0f  // B*HEADS*3*N
#define BNINV_ (1.0f / 32768.0f)

typedef __bf16 bf16x8 __attribute__((ext_vector_type(8)));
typedef float  f32x4  __attribute__((ext_vector_type(4)));

__device__ __forceinline__ unsigned short f2bf(float f) {
  unsigned int u = __float_as_uint(f);
  u = (u + 0x7FFFu + ((u >> 16) & 1u)) >> 16;   // round-to-nearest-even
  return (unsigned short)u;
}
__device__ __forceinline__ float bf2f(unsigned short s) {
  return __uint_as_float(((unsigned)s) << 16);
}

// ============================================================
// convW: W rows 24..535 -> bf16 [512][512]
// ============================================================
__global__ __launch_bounds__(256) void convw_kernel(const float* __restrict__ W,
                                                    unsigned short* __restrict__ Wbf) {
  int i = (blockIdx.x * 256 + threadIdx.x) * 4;
  float4 v = *(const float4*)&W[24 * 512 + i];
  ushort4 o;
  o.x = f2bf(v.x); o.y = f2bf(v.y); o.z = f2bf(v.z); o.w = f2bf(v.w);
  *(ushort4*)&Wbf[i] = o;
}

// ============================================================
// convXt: X[b][k][n] f32 -> Xt[b][n][k] bf16 (transposed)
// ============================================================
__global__ __launch_bounds__(256) void convxt_kernel(const float* __restrict__ X,
                                                     unsigned short* __restrict__ Xt) {
  const int n0 = blockIdx.x * 64;
  const int k0 = blockIdx.y * 64;
  const int b  = blockIdx.z;
  __shared__ float T[64][65];
  const int t = threadIdx.x;
#pragma unroll
  for (int i = 0; i < 16; ++i) {
    int idx = t + i * 256;
    int kk = idx >> 6, nn = idx & 63;
    T[kk][nn] = X[((size_t)b * MD_ + k0 + kk) * N_ + n0 + nn];
  }
  __syncthreads();
  const int sub = t & 7;
  const int nb  = t >> 3;
#pragma unroll
  for (int i = 0; i < 2; ++i) {
    int nn = nb + i * 32;
    ushort4 o0, o1;
    o0.x = f2bf(T[sub * 8 + 0][nn]); o0.y = f2bf(T[sub * 8 + 1][nn]);
    o0.z = f2bf(T[sub * 8 + 2][nn]); o0.w = f2bf(T[sub * 8 + 3][nn]);
    o1.x = f2bf(T[sub * 8 + 4][nn]); o1.y = f2bf(T[sub * 8 + 5][nn]);
    o1.z = f2bf(T[sub * 8 + 6][nn]); o1.w = f2bf(T[sub * 8 + 7][nn]);
    unsigned short* dst = Xt + ((size_t)b * N_ + n0 + nn) * MD_ + k0 + sub * 8;
    *(ushort4*)dst = o0;
    *(ushort4*)(dst + 4) = o1;
  }
}

// ============================================================
// gemm_mfma: fused GEMM dispatch.
//  blockIdx.y < 4 : bf16 MFMA for value channels -> valsbf
//  blockIdx.y == 4: fp32-exact keys GEMM (rows 0..23) -> kvk
// Both fuse per-channel stats into ssum/s2sum.
// ============================================================
__global__ __launch_bounds__(256) void gemm_mfma(const unsigned short* __restrict__ Wbf,
                                                 const unsigned short* __restrict__ Xt,
                                                 const float* __restrict__ W,
                                                 const float* __restrict__ X,
                                                 unsigned short* __restrict__ valsbf,
                                                 float* __restrict__ kvk,
                                                 float* __restrict__ ssum,
                                                 float* __restrict__ s2sum) {
  __shared__ __align__(16) unsigned short smem[128 * 144];  // 36 KB
  const int t = threadIdx.x;
  const int b = blockIdx.z;

  if (blockIdx.y == 4) {
    // ---- keys: fp32 GEMM, 24 rows x 128 cols per block ----
    const int n0 = blockIdx.x * 128;
    float* Wt = (float*)smem;             // [32][26]
    float* In = (float*)smem + 32 * 26;   // [32][132]
    const int cg = t & 31;                // col group (4 cols)
    const int rb = (t >> 5) * 3;          // 3 rows per group
    float acc[3][4];
#pragma unroll
    for (int r = 0; r < 3; ++r)
#pragma unroll
      for (int c = 0; c < 4; ++c) acc[r][c] = 0.f;
    const float* Xb = X + (size_t)b * MD_ * N_;
    for (int k0 = 0; k0 < MD_; k0 += 32) {
#pragma unroll
      for (int i = 0; i < 3; ++i) {
        int idx = t * 3 + i;              // 768 = 24*32
        int m = idx % 24, k = idx / 24;
        Wt[k * 26 + m] = W[(size_t)m * MD_ + k0 + k];
      }
#pragma unroll
      for (int i = 0; i < 4; ++i) {
        int slot = t + i * 256;           // 1024 float4 = 32 rows x 32
        int k = slot >> 5, n4 = slot & 31;
        float4 v = *(const float4*)(Xb + (size_t)(k0 + k) * N_ + n0 + n4 * 4);
        *(float4*)&In[k * 132 + n4 * 4] = v;
      }
      __syncthreads();
#pragma unroll
      for (int k = 0; k < 32; ++k) {
        float4 bv = *(const float4*)&In[k * 132 + cg * 4];
#pragma unroll
        for (int r = 0; r < 3; ++r) {
          float a = Wt[k * 26 + rb + r];
          acc[r][0] = fmaf(a, bv.x, acc[r][0]);
          acc[r][1] = fmaf(a, bv.y, acc[r][1]);
          acc[r][2] = fmaf(a, bv.z, acc[r][2]);
          acc[r][3] = fmaf(a, bv.w, acc[r][3]);
        }
      }
      __syncthreads();
    }
#pragma unroll
    for (int r = 0; r < 3; ++r) {
      float* dst = kvk + ((size_t)b * 24 + rb + r) * N_ + n0 + cg * 4;
      *(float4*)dst = *(float4*)&acc[r][0];
      float s = acc[r][0] + acc[r][1] + acc[r][2] + acc[r][3];
      float s2 = acc[r][0]*acc[r][0] + acc[r][1]*acc[r][1] +
                 acc[r][2]*acc[r][2] + acc[r][3]*acc[r][3];
#pragma unroll
      for (int off = 16; off; off >>= 1) {
        s  += __shfl_down(s, off, 32);
        s2 += __shfl_down(s2, off, 32);
      }
      if (cg == 0) { atomicAdd(&ssum[rb + r], s); atomicAdd(&s2sum[rb + r], s2); }
    }
    return;
  }

  // ---- values: bf16 MFMA 128x128 tile ----
#define AL(r, c) smem[(r) * 72 + (c)]
#define BL(r, c) smem[128 * 72 + (r) * 72 + (c)]
#define CS(r, c) smem[(r) * 136 + (c)]
  const int n0 = blockIdx.x * 128;
  const int m0 = blockIdx.y * 128;
  const int lane = t & 63, wave = t >> 6;
  const int wm = wave >> 1, wn = wave & 1;
  f32x4 acc[4][4];
#pragma unroll
  for (int mi = 0; mi < 4; ++mi)
#pragma unroll
    for (int ni = 0; ni < 4; ++ni)
#pragma unroll
      for (int j = 0; j < 4; ++j) acc[mi][ni][j] = 0.f;

  const unsigned short* Xb = Xt + ((size_t)b * N_ + n0) * MD_;
  for (int k0 = 0; k0 < MD_; k0 += 64) {
#pragma unroll
    for (int i = 0; i < 4; ++i) {
      int chunk = t + i * 256;
      int r = chunk >> 3, c = chunk & 7;
      *(uint4*)&AL(r, c * 8) =
          *(const uint4*)&Wbf[(size_t)(m0 + r) * MD_ + k0 + c * 8];
    }
#pragma unroll
    for (int i = 0; i < 4; ++i) {
      int chunk = t + i * 256;
      int r = chunk >> 3, c = chunk & 7;
      *(uint4*)&BL(r, c * 8) =
          *(const uint4*)&Xb[(size_t)r * MD_ + k0 + c * 8];
    }
    __syncthreads();
#pragma unroll
    for (int ks = 0; ks < 2; ++ks) {
      bf16x8 af[4], bfr[4];
#pragma unroll
      for (int mi = 0; mi < 4; ++mi)
        af[mi] = *(const bf16x8*)&AL(wm * 64 + mi * 16 + (lane & 15),
                                     ks * 32 + (lane >> 4) * 8);
#pragma unroll
      for (int ni = 0; ni < 4; ++ni)
        bfr[ni] = *(const bf16x8*)&BL(wn * 64 + ni * 16 + (lane & 15),
                                      ks * 32 + (lane >> 4) * 8);
#pragma unroll
      for (int mi = 0; mi < 4; ++mi)
#pragma unroll
        for (int ni = 0; ni < 4; ++ni)
          acc[mi][ni] = __builtin_amdgcn_mfma_f32_16x16x32_bf16(
              af[mi], bfr[ni], acc[mi][ni], 0, 0, 0);
    }
    __syncthreads();
  }
  // fused stats (fp32, before bf16 rounding)
#pragma unroll
  for (int mi = 0; mi < 4; ++mi)
#pragma unroll
    for (int j = 0; j < 4; ++j) {
      float s  = acc[mi][0][j] + acc[mi][1][j] + acc[mi][2][j] + acc[mi][3][j];
      float s2 = acc[mi][0][j]*acc[mi][0][j] + acc[mi][1][j]*acc[mi][1][j] +
                 acc[mi][2][j]*acc[mi][2][j] + acc[mi][3][j]*acc[mi][3][j];
#pragma unroll
      for (int off = 1; off < 16; off <<= 1) {
        s  += __shfl_xor(s, off);
        s2 += __shfl_xor(s2, off);
      }
      if ((lane & 15) == 0) {
        int mg = m0 + wm * 64 + mi * 16 + (lane >> 4) * 4 + j;
        atomicAdd(&ssum[24 + mg], s);
        atomicAdd(&s2sum[24 + mg], s2);
      }
    }
  // stage bf16 C-tile in LDS; coalesced writeback
#pragma unroll
  for (int mi = 0; mi < 4; ++mi)
#pragma unroll
    for (int ni = 0; ni < 4; ++ni) {
      int row = wm * 64 + mi * 16 + (lane >> 4) * 4;
      int col = wn * 64 + ni * 16 + (lane & 15);
#pragma unroll
      for (int j = 0; j < 4; ++j)
        CS(row + j, col) = f2bf(acc[mi][ni][j]);
    }
  __syncthreads();
#pragma unroll
  for (int i = 0; i < 4; ++i) {
    int row = (t >> 3) + i * 32;
    int cb  = (t & 7) * 16;
    uint4 lo = *(const uint4*)&CS(row, cb);
    uint4 hi = *(const uint4*)&CS(row, cb + 8);
    unsigned short* dst = valsbf + ((size_t)b * 512 + m0 + row) * N_ + n0 + cb;
    *(uint4*)dst       = lo;
    *(uint4*)(dst + 8) = hi;
  }
#undef AL
#undef BL
#undef CS
}

// ============================================================
// sortk (passk fused): per-bh — compute keys/cells inline,
// counting-sort points by cell, keys mean/var partials.
// Output: sorted[bh][i] = {r0,r1,r2, bitcast(cell | n<<15)}
// ============================================================
__global__ __launch_bounds__(1024, 1) void sortk_kernel(const float* __restrict__ kvk,
                                                        const float* __restrict__ orig,
                                                        const float* __restrict__ proj,
                                                        const float* __restrict__ ssum,
                                                        const float* __restrict__ s2sum,
                                                        const float* __restrict__ kg,
                                                        const float* __restrict__ kb,
                                                        float4* __restrict__ sorted,
                                                        float* __restrict__ kacc) {
  const int bh = blockIdx.x;
  const int b = bh >> 3, h = bh & 7;
  __shared__ int hist[NC_];      // 128 KiB
  __shared__ int wsum[16];
  const int t = threadIdx.x;
  for (int i = t; i < NC_; i += 1024) hist[i] = 0;

  // BN finalize for this head's 3 key channels (uniform)
  float sck[3], shk[3];
#pragma unroll
  for (int k = 0; k < 3; ++k) {
    int ch = h * 3 + k;
    float mu  = ssum[ch] * BNINV_;
    float var = s2sum[ch] * BNINV_ - mu * mu;
    sck[k] = kg[ch] * rsqrtf(var + 1e-5f);
    shk[k] = kb[ch] - mu * sck[k];
  }
  __syncthreads();

  const float* Kb = kvk + (size_t)b * 24 * N_;
  const float* Ob = orig + (size_t)b * 3 * N_;
  float4 mreg[8];
  float ksum = 0.f, ksq = 0.f;
#pragma unroll
  for (int i = 0; i < 8; ++i) {
    const int n = t + i * 1024;
    float pt[3];
#pragma unroll
    for (int k = 0; k < 3; ++k) {
      float kr = fmaf(Kb[(size_t)(h * 3 + k) * N_ + n], sck[k], shk[k]);
      pt[k] = Ob[(size_t)k * N_ + n] + kr;
    }
    int cell = 0;
    float rr[3];
#pragma unroll
    for (int d = 0; d < 3; ++d) {
      const float* pr = proj + (h * 3 + d) * 3;
      float key = pr[0] * pt[0] + pr[1] * pt[1] + pr[2] * pt[2];
      ksum += key; ksq += key * key;
      float lat = tanhf(key);
      float c = (lat + 1.0f) * 15.5f;
      float fl = floorf(c);
      fl = fminf(fmaxf(fl, 0.0f), 30.0f);
      rr[d] = c - fl;
      cell += (int)fl * ((d == 0) ? 1024 : (d == 1) ? 32 : 1);
    }
    mreg[i] = make_float4(rr[0], rr[1], rr[2], __int_as_float(cell | (n << 15)));
    atomicAdd(&hist[cell], 1);
  }
#pragma unroll
  for (int off = 32; off; off >>= 1) {
    ksum += __shfl_down(ksum, off);
    ksq  += __shfl_down(ksq, off);
  }
  if ((t & 63) == 0) {
    atomicAdd(&kacc[0], ksum);
    atomicAdd(&kacc[1], ksq);
  }
  __syncthreads();

  const int base = t * 32;
  int s = 0;
#pragma unroll
  for (int j = 0; j < 32; ++j) s += hist[base + ((j + t) & 31)];
  const int lane = t & 63, wv = t >> 6;
  int sc = s;
#pragma unroll
  for (int off = 1; off < 64; off <<= 1) {
    int x = __shfl_up(sc, off);
    if (lane >= off) sc += x;
  }
  if (lane == 63) wsum[wv] = sc;
  __syncthreads();
  if (t < 16) {
    int x = wsum[t];
    int sc2 = x;
#pragma unroll
    for (int off = 1; off < 16; off <<= 1) {
      int y = __shfl_up(sc2, off);
      if (t >= off) sc2 += y;
    }
    wsum[t] = sc2 - x;
  }
  __syncthreads();
  int run = sc - s + wsum[wv];
#pragma unroll
  for (int j = 0; j < 32; ++j) {
    int idx = base + ((j + t) & 31);
    int v = hist[idx];
    hist[idx] = run;
    run += v;
  }
  __syncthreads();
  float4* dst = sorted + (size_t)bh * N_;
#pragma unroll
  for (int i = 0; i < 8; ++i) {
    float4 m = mreg[i];
    int cell = __float_as_int(m.w) & 32767;
    int pos = atomicAdd(&hist[cell], 1);
    dst[pos] = m;
  }
}

// ============================================================
// accum (R13 structure + LDS-staged value row): block = (bh,f),
// full 32^3 grid tile (128 KB) + 16 KB bf16 kv row in LDS.
// Thread owns 16 consecutive sorted entries; register run-merge
// with Z-SLIDE; BN inlined; coalesced non-atomic z write + occ.
// ============================================================
__global__ __launch_bounds__(512, 1) void accum_kernel(const unsigned short* __restrict__ valsbf,
                                                       const float* __restrict__ ssum,
                                                       const float* __restrict__ s2sum,
                                                       const float* __restrict__ vg,
                                                       const float* __restrict__ vb,
                                                       const float4* __restrict__ sorted,
                                                       float* __restrict__ zout,
                                                       unsigned int* __restrict__ occ) {
  const int blk = blockIdx.x;       // bh*64 + f
  const int f   = blk & 63;
  const int bh  = blk >> 6;
  const int b = bh >> 3, h = bh & 7;
  __shared__ float tile[NC_];               // 128 KiB
  __shared__ unsigned short kvs[N_];        // 16 KiB
  const int t = threadIdx.x;
#pragma unroll
  for (int i = 0; i < 16; ++i)
    ((float4*)tile)[t + i * 512] = make_float4(0.f, 0.f, 0.f, 0.f);
  const unsigned short* kvrow = valsbf + ((size_t)b * 512 + h * 64 + f) * N_;
  ((uint4*)kvs)[t]       = ((const uint4*)kvrow)[t];
  ((uint4*)kvs)[t + 512] = ((const uint4*)kvrow)[t + 512];
  __syncthreads();

  const int ch = 24 + h * 64 + f;
  const float mu  = ssum[ch] * BNINV_;
  const float var = s2sum[ch] * BNINV_ - mu * mu;
  const float sc  = vg[ch - 24] * rsqrtf(var + 1e-5f);
  const float sh  = vb[ch - 24] - mu * sc;
  const float4* sp = sorted + (size_t)bh * N_;
  const int base = t * 16;

  float4 e[16];
#pragma unroll
  for (int i = 0; i < 16; ++i) e[i] = sp[base + i];

#define FLUSH8()                                                    \
  {                                                                 \
    atomicAdd(&tile[cur],        m0_);                              \
    atomicAdd(&tile[cur + 1],    m1_);                              \
    atomicAdd(&tile[cur + 32],   m2_);                              \
    atomicAdd(&tile[cur + 33],   m3_);                              \
    atomicAdd(&tile[cur + 1024], m4_);                              \
    atomicAdd(&tile[cur + 1025], m5_);                              \
    atomicAdd(&tile[cur + 1056], m6_);                              \
    atomicAdd(&tile[cur + 1057], m7_);                              \
  }

  float m0_ = 0.f, m1_ = 0.f, m2_ = 0.f, m3_ = 0.f;
  float m4_ = 0.f, m5_ = 0.f, m6_ = 0.f, m7_ = 0.f;
  int cur = __float_as_int(e[0].w) & 32767;
#pragma unroll
  for (int i = 0; i < 16; ++i) {
    int packed = __float_as_int(e[i].w);
    int cell = packed & 32767;
    if (cell != cur) {
      if (cell == cur + 1) {
        atomicAdd(&tile[cur],        m0_);
        atomicAdd(&tile[cur + 32],   m2_);
        atomicAdd(&tile[cur + 1024], m4_);
        atomicAdd(&tile[cur + 1056], m6_);
        m0_ = m1_; m2_ = m3_; m4_ = m5_; m6_ = m7_;
        m1_ = 0.f; m3_ = 0.f; m5_ = 0.f; m7_ = 0.f;
      } else {
        FLUSH8();
        m0_ = m1_ = m2_ = m3_ = m4_ = m5_ = m6_ = m7_ = 0.f;
      }
      cur = cell;
    }
    float v  = fmaf(bf2f(kvs[(unsigned)packed >> 15]), sc, sh);
    float r0 = e[i].x, r1 = e[i].y, r2 = e[i].z;
    float va = v * (1.f - r0), vb2 = v * r0;
    float c00 = (1.f - r1) * (1.f - r2), c01 = (1.f - r1) * r2;
    float c10 = r1 * (1.f - r2),         c11 = r1 * r2;
    m0_ = fmaf(va, c00, m0_); m1_ = fmaf(va, c01, m1_);
    m2_ = fmaf(va, c10, m2_); m3_ = fmaf(va, c11, m3_);
    m4_ = fmaf(vb2, c00, m4_); m5_ = fmaf(vb2, c01, m5_);
    m6_ = fmaf(vb2, c10, m6_); m7_ = fmaf(vb2, c11, m7_);
  }
  FLUSH8();
#undef FLUSH8
  __syncthreads();

  unsigned int cnt = 0;
  float* dst = zout + (size_t)blk * NC_;
#pragma unroll
  for (int i = 0; i < 16; ++i) {
    float4 v = ((const float4*)tile)[t + i * 512];
    cnt += (fabsf(v.x) > 1e-9f) ? 1u : 0u;
    cnt += (fabsf(v.y) > 1e-9f) ? 1u : 0u;
    cnt += (fabsf(v.z) > 1e-9f) ? 1u : 0u;
    cnt += (fabsf(v.w) > 1e-9f) ? 1u : 0u;
    ((float4*)dst)[t + i * 512] = v;
  }
#pragma unroll
  for (int off = 32; off; off >>= 1) cnt += __shfl_down(cnt, off);
  __shared__ unsigned int wc[8];
  if ((t & 63) == 0) wc[t >> 6] = cnt;
  __syncthreads();
  if (t == 0) {
    unsigned int s = 0;
#pragma unroll
    for (int i = 0; i < 8; ++i) s += wc[i];
    atomicAdd(occ, s);
  }
}

// ============================================================
// fallback path (small ws): fp32 everything, direct splat
// ============================================================
__global__ __launch_bounds__(256) void gemm_full_kernel(const float* __restrict__ W,
                                                        const float* __restrict__ X,
                                                        float* __restrict__ KV) {
  const int n0 = blockIdx.x * 256;
  const int m0 = blockIdx.y * 64;
  const int b  = blockIdx.z;
  __shared__ float Wt[32][68];
  __shared__ float In[32][260];
  const int t  = threadIdx.x;
  const int tx = t & 31;
  const int ty = t >> 5;
  float acc[8][8];
#pragma unroll
  for (int r = 0; r < 8; ++r)
#pragma unroll
    for (int c = 0; c < 8; ++c) acc[r][c] = 0.f;
  const float* Xb = X + (size_t)b * MD_ * N_;
  for (int k0 = 0; k0 < MD_; k0 += 32) {
#pragma unroll
    for (int i = 0; i < 8; ++i) {
      int idx = t + i * 256;
      int m = idx >> 5, k = idx & 31;
      int mm = m0 + m;
      Wt[k][m] = (mm < OC_) ? W[(size_t)mm * MD_ + (k0 + k)] : 0.f;
    }
#pragma unroll
    for (int i = 0; i < 8; ++i) {
      int slot = t + i * 256;
      int k = slot >> 6, n4 = slot & 63;
      float4 v = *(const float4*)(Xb + (size_t)(k0 + k) * N_ + n0 + n4 * 4);
      *(float4*)&In[k][n4 * 4] = v;
    }
    __syncthreads();
#pragma unroll
    for (int k = 0; k < 32; ++k) {
      float a[8], bb[8];
      *(float4*)&a[0]  = *(const float4*)&Wt[k][ty * 8];
      *(float4*)&a[4]  = *(const float4*)&Wt[k][ty * 8 + 4];
      *(float4*)&bb[0] = *(const float4*)&In[k][tx * 4];
      *(float4*)&bb[4] = *(const float4*)&In[k][128 + tx * 4];
#pragma unroll
      for (int r = 0; r < 8; ++r)
#pragma unroll
        for (int c = 0; c < 8; ++c)
          acc[r][c] = fmaf(a[r], bb[c], acc[r][c]);
    }
    __syncthreads();
  }
#pragma unroll
  for (int r = 0; r < 8; ++r) {
    int mm = m0 + ty * 8 + r;
    if (mm < OC_) {
      float* dst = KV + ((size_t)b * OC_ + mm) * N_ + n0;
      *(float4*)(dst + tx * 4)       = *(float4*)&acc[r][0];
      *(float4*)(dst + 128 + tx * 4) = *(float4*)&acc[r][4];
    }
  }
}

__global__ __launch_bounds__(256) void bn_kernel(const float* __restrict__ KV,
                                                 const float* __restrict__ kg,
                                                 const float* __restrict__ kb,
                                                 const float* __restrict__ vg,
                                                 const float* __restrict__ vb,
                                                 float* __restrict__ scale,
                                                 float* __restrict__ shift) {
  const int o = blockIdx.x;
  const int t = threadIdx.x;
  float s = 0.f, s2 = 0.f;
  for (int idx = t; idx < B_ * N_; idx += 256) {
    int bb = idx >> 13, n = idx & (N_ - 1);
    float v = KV[((size_t)bb * OC_ + o) * N_ + n];
    s += v; s2 = fmaf(v, v, s2);
  }
#pragma unroll
  for (int off = 32; off; off >>= 1) {
    s  += __shfl_down(s, off);
    s2 += __shfl_down(s2, off);
  }
  __shared__ float rs[4], rs2[4];
  if ((t & 63) == 0) { rs[t >> 6] = s; rs2[t >> 6] = s2; }
  __syncthreads();
  if (t == 0) {
    s  = rs[0] + rs[1] + rs[2] + rs[3];
    s2 = rs2[0] + rs2[1] + rs2[2] + rs2[3];
    const float inv = 1.0f / (B_ * N_);
    float mu  = s * inv;
    float var = s2 * inv - mu * mu;
    float g, be;
    if (o < 24) { g = kg[o]; be = kb[o]; }
    else        { g = vg[o - 24]; be = vb[o - 24]; }
    float sc = g * rsqrtf(var + 1e-5f);
    scale[o] = sc;
    shift[o] = be - mu * sc;
  }
}

__global__ __launch_bounds__(256) void splat_final_kernel(const float* __restrict__ KV,
                                                          const float* __restrict__ orig,
                                                          const float* __restrict__ proj,
                                                          const float* __restrict__ scale,
                                                          const float* __restrict__ shift,
                                                          float* __restrict__ Z,
                                                          float* __restrict__ kacc) {
  const int bh = blockIdx.x >> 7;
  const int n0 = (blockIdx.x & 127) << 6;
  const int b = bh >> 3, h = bh & 7;
  __shared__ float vals[64][65];
  __shared__ int   cellS[64];
  __shared__ float rS[64][4];
  const int t = threadIdx.x;
  const float* KVb = KV + (size_t)b * OC_ * N_;
  const int ch0 = 24 + h * 64;
#pragma unroll
  for (int i = 0; i < 16; ++i) {
    int idx = t + i * 256;
    int f = idx >> 6, p = idx & 63;
    int ch = ch0 + f;
    vals[f][p] = fmaf(KVb[(size_t)ch * N_ + n0 + p], scale[ch], shift[ch]);
  }
  if (t < 64) {
    const int n = n0 + t;
    float pt[3];
#pragma unroll
    for (int k = 0; k < 3; ++k) {
      int ch = h * 3 + k;
      float kr = fmaf(KVb[(size_t)ch * N_ + n], scale[ch], shift[ch]);
      pt[k] = orig[((size_t)b * 3 + k) * N_ + n] + kr;
    }
    float ksum = 0.f, ksq = 0.f;
    int cell = 0;
    float rr[3];
#pragma unroll
    for (int d = 0; d < 3; ++d) {
      const float* pr = proj + (h * 3 + d) * 3;
      float key = pr[0] * pt[0] + pr[1] * pt[1] + pr[2] * pt[2];
      ksum += key; ksq += key * key;
      float lat = tanhf(key);
      float c = (lat + 1.0f) * 15.5f;
      float fl = floorf(c);
      fl = fminf(fmaxf(fl, 0.0f), 30.0f);
      rr[d] = c - fl;
      cell += (int)fl * ((d == 0) ? 1024 : (d == 1) ? 32 : 1);
    }
    cellS[t] = cell;
    rS[t][0] = rr[0]; rS[t][1] = rr[1]; rS[t][2] = rr[2];
#pragma unroll
    for (int off = 32; off; off >>= 1) {
      ksum += __shfl_down(ksum, off);
      ksq  += __shfl_down(ksq, off);
    }
    if (t == 0) { atomicAdd(&kacc[0], ksum); atomicAdd(&kacc[1], ksq); }
  }
  __syncthreads();
  const int w = t >> 6, l = t & 63;
  for (int pi = 0; pi < 16; ++pi) {
    int p = w * 16 + pi;
    int cell = cellS[p];
    float r0 = rS[p][0], r1 = rS[p][1], r2 = rS[p][2];
    float u0 = 1.f - r0, u1 = 1.f - r1, u2 = 1.f - r2;
    float v = vals[l][p];
#pragma unroll
    for (int c = 0; c < 8; ++c) {
      float wt = ((c & 4) ? r0 : u0) * ((c & 2) ? r1 : u1) * ((c & 1) ? r2 : u2);
      int cc = cell + ((c & 4) ? 1024 : 0) + ((c & 2) ? 32 : 0) + (c & 1);
      atomicAdd(Z + (size_t)(bh * 64 + l) * NC_ + cc, v * wt);
    }
  }
}

__global__ __launch_bounds__(256) void count_kernel(const float* __restrict__ Z,
                                                    unsigned int* __restrict__ occ) {
  unsigned int cnt = 0;
  for (long long i = (long long)blockIdx.x * blockDim.x + threadIdx.x; i < ZTOT_;
       i += (long long)gridDim.x * blockDim.x)
    cnt += (fabsf(Z[i]) > 1e-9f) ? 1u : 0u;
#pragma unroll
  for (int off = 32; off; off >>= 1) cnt += __shfl_down(cnt, off);
  __shared__ unsigned int wc[4];
  const int t = threadIdx.x;
  if ((t & 63) == 0) wc[t >> 6] = cnt;
  __syncthreads();
  if (t == 0) atomicAdd(occ, wc[0] + wc[1] + wc[2] + wc[3]);
}

__global__ void finalize_kernel(const unsigned int* __restrict__ occ,
                                const float* __restrict__ kacc,
                                float* __restrict__ tail) {
  float mean = kacc[0] / NKEYS_;
  tail[0] = (float)(*occ) * (1.0f / 2048.0f);
  tail[1] = mean;
  tail[2] = kacc[1] / NKEYS_ - mean * mean;
}

// ============================================================
extern "C" void kernel_launch(void* const* d_in, const int* in_sizes, int n_in,
                              void* d_out, int out_size, void* d_ws, size_t ws_size,
                              hipStream_t stream) {
  const float* X    = (const float*)d_in[0];
  const float* orig = (const float*)d_in[1];
  const float* W    = (const float*)d_in[2];
  const float* kg   = (const float*)d_in[3];
  const float* kb   = (const float*)d_in[4];
  const float* vg   = (const float*)d_in[5];
  const float* vb   = (const float*)d_in[6];
  const float* proj = (const float*)d_in[7];
  float* out = (float*)d_out;

  float* P = (float*)d_ws;
  float* ssum  = P;                         // [544]
  float* s2sum = P + 544;                   // [544]
  float* kacc  = P + 1088;                  // [2]
  unsigned int* occ = (unsigned int*)(P + 1090);
  float* scale = P + 1152;                  // [536] (fallback only)
  float* shift = P + 1696;                  // [536] (fallback only)
  char* wsb = (char*)d_ws;

  const size_t need = (size_t)60 << 20;
  if (ws_size >= need) {
    unsigned short* Wbf    = (unsigned short*)(wsb + 65536);        // 512 KB
    float*          kvk    = (float*)(wsb + ((size_t)1 << 20));     // 3 MB
    float4*         sorted = (float4*)(wsb + ((size_t)5 << 20));    // 4 MB
    unsigned short* valsbf = (unsigned short*)(wsb + ((size_t)9 << 20)); // 33.6 MB
    // staging in d_out's z region (consumed before accum writes z)
    unsigned short* Xt = (unsigned short*)out;                      // 32 MB

    hipMemsetAsync(P, 0, 4368, stream);

    convw_kernel<<<256, 256, 0, stream>>>(W, Wbf);
    convxt_kernel<<<dim3(128, 8, 4), 256, 0, stream>>>(X, Xt);
    gemm_mfma<<<dim3(64, 5, 4), 256, 0, stream>>>(Wbf, Xt, W, X,
                                                  valsbf, kvk, ssum, s2sum);
    sortk_kernel<<<32, 1024, 0, stream>>>(kvk, orig, proj, ssum, s2sum,
                                          kg, kb, sorted, kacc);
    accum_kernel<<<2048, 512, 0, stream>>>(valsbf, ssum, s2sum, vg, vb,
                                           sorted, out, occ);
    finalize_kernel<<<1, 1, 0, stream>>>(occ, kacc, out + ZTOT_);
  } else {
    float* kv = (float*)(wsb + 16384);
    hipMemsetAsync(P, 0, 4368, stream);
    hipMemsetAsync(out, 0, (size_t)ZTOT_ * 4, stream);
    gemm_full_kernel<<<dim3(N_ / 256, 9, B_), 256, 0, stream>>>(W, X, kv);
    bn_kernel<<<OC_, 256, 0, stream>>>(kv, kg, kb, vg, vb, scale, shift);
    splat_final_kernel<<<B_ * HEADS_ * (N_ / 64), 256, 0, stream>>>(
        kv, orig, proj, scale, shift, out, kacc);
    count_kernel<<<2048, 256, 0, stream>>>(out, occ);
    finalize_kernel<<<1, 1, 0, stream>>>(occ, kacc, out + ZTOT_);
  }
}